// Round 11
// baseline (744.685 us; speedup 1.0000x reference)
//
#include <hip/hip_runtime.h>
#include <math.h>

#define BB 8
#define CC 512
#define TT 2048
#define ICC 256
#define EPSV 1e-5f
#define SC2048 2048.0f
#define INV2048 4.8828125e-4f

typedef _Float16 f16;
typedef __attribute__((ext_vector_type(8))) _Float16 f16x8;
typedef __attribute__((ext_vector_type(4))) float f32x4;

#define MFMA(a, b, c) __builtin_amdgcn_mfma_f32_16x16x32_f16(a, b, c, 0, 0, 0)

__device__ __forceinline__ int swz(int byte, int row) {
  return byte ^ ((row & 7) << 4);
}

// ---------------------------------------------------------------------------
// P0: x[b][c][t] f32 -> xT hi / scaled-lo f16 [b][t][c]
// ---------------------------------------------------------------------------
__global__ __launch_bounds__(256) void split_transpose_x(
    const float* __restrict__ x, f16* __restrict__ xh, f16* __restrict__ xl) {
  __shared__ float tile[32][33];
  const int tx = threadIdx.x, ty = threadIdx.y;
  const int t0 = blockIdx.x * 32, c0 = blockIdx.y * 32, b = blockIdx.z;
#pragma unroll
  for (int k = 0; k < 4; ++k)
    tile[ty + 8 * k][tx] = x[((size_t)b * CC + c0 + ty + 8 * k) * TT + t0 + tx];
  __syncthreads();
#pragma unroll
  for (int k = 0; k < 4; ++k) {
    float v = tile[tx][ty + 8 * k];
    size_t o = ((size_t)b * TT + t0 + ty + 8 * k) * CC + c0 + tx;
    f16 h = (f16)v;
    xh[o] = h;
    xl[o] = (f16)((v - (float)h) * SC2048);
  }
}

__global__ void split_w(const float* __restrict__ src, f16* __restrict__ h,
                        f16* __restrict__ lo, int n) {
  int i = blockIdx.x * 256 + threadIdx.x;
  if (i < n) {
    float v = src[i];
    f16 a = (f16)v;
    h[i] = a;
    lo[i] = (f16)((v - (float)a) * SC2048);
  }
}

// ---------------------------------------------------------------------------
// NT GEMM (verified): D = A*B^T + bias, split-f16.
// ---------------------------------------------------------------------------
template <int M, int N, int K, bool BIAS_N, bool F32OUT>
__global__ __launch_bounds__(256) void gemm_nt(
    const f16* __restrict__ Ah, const f16* __restrict__ Al, long strideA,
    const f16* __restrict__ Bh, const f16* __restrict__ Bl, long strideB,
    const float* __restrict__ bias, f16* __restrict__ Oh, f16* __restrict__ Ol,
    float* __restrict__ Of, long strideO, double* __restrict__ osum,
    double* __restrict__ osumsq) {
  __shared__ f16 sAh[4096], sAl[4096], sBh[4096], sBl[4096];
  __shared__ float sOut[F32OUT ? 1 : 32 * 132];
  const int tid = threadIdx.x;
  const int w = tid >> 6, l = tid & 63;
  const int bn = blockIdx.x * 128, bm = blockIdx.y * 128;
  const size_t baseA = (size_t)blockIdx.z * strideA;
  const size_t baseB = (size_t)blockIdx.z * strideB;
  const size_t baseO = (size_t)blockIdx.z * strideO;
  const int m0 = (w >> 1) * 64, n0 = (w & 1) * 64;
  char* cAh = (char*)sAh;
  char* cAl = (char*)sAl;
  char* cBh = (char*)sBh;
  char* cBl = (char*)sBl;

  f32x4 acc[4][4], accL[4][4];
#pragma unroll
  for (int i = 0; i < 4; ++i)
#pragma unroll
    for (int j = 0; j < 4; ++j) {
      acc[i][j] = (f32x4){0.f, 0.f, 0.f, 0.f};
      accL[i][j] = (f32x4){0.f, 0.f, 0.f, 0.f};
    }

  for (int kb = 0; kb < K; kb += 32) {
    __syncthreads();
#pragma unroll
    for (int rep = 0; rep < 2; ++rep) {
      int slot = tid + rep * 256;
      int row = slot >> 2, ks = slot & 3;
      int byte = swz(row * 64 + ks * 16, row);
      size_t ga = baseA + (size_t)(bm + row) * K + kb + ks * 8;
      size_t gb = baseB + (size_t)(bn + row) * K + kb + ks * 8;
      *(f16x8*)(cAh + byte) = *(const f16x8*)(Ah + ga);
      *(f16x8*)(cAl + byte) = *(const f16x8*)(Al + ga);
      *(f16x8*)(cBh + byte) = *(const f16x8*)(Bh + gb);
      *(f16x8*)(cBl + byte) = *(const f16x8*)(Bl + gb);
    }
    __syncthreads();
    f16x8 ah[4], al[4];
#pragma unroll
    for (int mf = 0; mf < 4; ++mf) {
      int row = m0 + mf * 16 + (l & 15);
      int byte = swz(row * 64 + ((l >> 4) << 4), row);
      ah[mf] = *(const f16x8*)(cAh + byte);
      al[mf] = *(const f16x8*)(cAl + byte);
    }
#pragma unroll
    for (int nf = 0; nf < 4; ++nf) {
      int row = n0 + nf * 16 + (l & 15);
      int byte = swz(row * 64 + ((l >> 4) << 4), row);
      f16x8 bh = *(const f16x8*)(cBh + byte);
      f16x8 bl = *(const f16x8*)(cBl + byte);
#pragma unroll
      for (int mf = 0; mf < 4; ++mf)
        acc[mf][nf] = MFMA(ah[mf], bh, acc[mf][nf]);
#pragma unroll
      for (int mf = 0; mf < 4; ++mf)
        accL[mf][nf] = MFMA(al[mf], bh, accL[mf][nf]);
#pragma unroll
      for (int mf = 0; mf < 4; ++mf)
        accL[mf][nf] = MFMA(ah[mf], bl, accL[mf][nf]);
    }
  }

  if (F32OUT) {
#pragma unroll
    for (int mf = 0; mf < 4; ++mf)
#pragma unroll
      for (int r = 0; r < 4; ++r) {
        int mrow = bm + m0 + mf * 16 + ((l >> 4) << 2) + r;
        float bv = bias[mrow];
        double s = 0.0, q = 0.0;
#pragma unroll
        for (int nf = 0; nf < 4; ++nf) {
          float v = acc[mf][nf][r] + accL[mf][nf][r] * INV2048 + bv;
          Of[baseO + (size_t)mrow * N + bn + n0 + nf * 16 + (l & 15)] = v;
          s += (double)v;
          q += (double)v * (double)v;
        }
#pragma unroll
        for (int sh = 8; sh >= 1; sh >>= 1) {
          s += __shfl_xor(s, sh);
          q += __shfl_xor(q, sh);
        }
        if ((l & 15) == 0) {
          atomicAdd(&osum[mrow], s);
          atomicAdd(&osumsq[mrow], q);
        }
      }
  } else {
    for (int c = 0; c < 4; ++c) {
      __syncthreads();
      if ((w >> 1) == (c >> 1)) {
#pragma unroll
        for (int mf2 = 0; mf2 < 2; ++mf2) {
          int mf = (c & 1) * 2 + mf2;
          int rl = m0 - c * 32 + mf * 16 + ((l >> 4) << 2);
#pragma unroll
          for (int nf = 0; nf < 4; ++nf)
#pragma unroll
            for (int r = 0; r < 4; ++r)
              sOut[(rl + r) * 132 + n0 + nf * 16 + (l & 15)] =
                  acc[mf][nf][r] + accL[mf][nf][r] * INV2048;
        }
      }
      __syncthreads();
      int row = tid >> 3, cc0 = (tid & 7) * 16;
      size_t gm = bm + c * 32 + row;
      size_t ob = baseO + gm * (size_t)N + bn + cc0;
      f16 hv[16], lv[16];
#pragma unroll
      for (int e = 0; e < 16; ++e) {
        float v = sOut[row * 132 + cc0 + e];
        v += BIAS_N ? bias[bn + cc0 + e] : bias[gm];
        f16 h = (f16)v;
        hv[e] = h;
        lv[e] = (f16)((v - (float)h) * SC2048);
      }
      *(f16x8*)&Oh[ob] = *(f16x8*)hv;
      *(f16x8*)&Oh[ob + 8] = *(f16x8*)(hv + 8);
      *(f16x8*)&Ol[ob] = *(f16x8*)lv;
      *(f16x8*)&Ol[ob + 8] = *(f16x8*)(lv + 8);
    }
  }
}

// ---------------------------------------------------------------------------
// Fused flash attention v4.1 (r11): split-K across blocks (r10, verified) +
// register-diet for 2 blocks/CU:
//  - ql (theta_lo) no longer a persistent register array: loaded per-use
//    from global; each block's 32KB theta_lo slice is L1-resident after
//    chunk 0 (32KB L1/CU).
//  - __launch_bounds__(256, 2): REQUIRE 2 waves/EU -> allocator must fit
//    <=256 total regs (arch VGPR + AGPR) -> 2 blocks/CU co-resident.
//    (r6-r10 ran 1 block/CU: ~236 arch + 128 AGPR accumulators = ~364.)
// ---------------------------------------------------------------------------
__global__ __launch_bounds__(256, 2) void attn_mfma(
    const f16* __restrict__ th_h, const f16* __restrict__ th_l,
    const f16* __restrict__ ph_h, const f16* __restrict__ ph_l,
    const f16* __restrict__ g_h, const f16* __restrict__ g_l,
    float* __restrict__ yp, float* __restrict__ mlb) {
  __shared__ char U[33792];            // phi chunk <-> g chunk <-> f32 out
  __shared__ f16 sP[2048], sPl[2048];  // P hi / scaled-lo [64][32] swizzled
  __shared__ float sSc[64];
  const int tid = threadIdx.x, w = tid >> 6, l = tid & 63;
  const int b = blockIdx.x & 7;
  const int i0 = ((blockIdx.x >> 3) & 31) * 64;
  const int ks = blockIdx.x >> 8;  // key-split 0/1

  const size_t tbase =
      ((size_t)b * TT + i0 + w * 16 + (l & 15)) * 256 + ((l >> 4) << 3);
  f16x8 qh[8];
#pragma unroll
  for (int kf = 0; kf < 8; ++kf) qh[kf] = *(const f16x8*)(th_h + tbase + kf * 32);
  f32x4 yacc[4][4], yaccL[4][4];
#pragma unroll
  for (int i = 0; i < 4; ++i)
#pragma unroll
    for (int j = 0; j < 4; ++j) {
      yacc[i][j] = (f32x4){0.f, 0.f, 0.f, 0.f};
      yaccL[i][j] = (f32x4){0.f, 0.f, 0.f, 0.f};
    }
  float mrow[4], lrow[4];
#pragma unroll
  for (int r = 0; r < 4; ++r) {
    mrow[r] = -3e38f;
    lrow[r] = 0.f;
  }
  f16* Ph = (f16*)U;
  f16* Pl = Ph + 8192;  // phi: [32][256] hi, lo'
  f16* Gh = (f16*)U;
  f16* Gl = Gh + 8192;  // g:   [256][32] hi, lo' (time-shared with phi)

  for (int jc = ks * 32; jc < ks * 32 + 32; ++jc) {
    const int j0 = jc * 32;
    // ---- stage phi chunk [32 j][256 c]
#pragma unroll
    for (int rep = 0; rep < 4; ++rep) {
      int slot = tid + rep * 256;
      int row = slot >> 5, kq = slot & 31;
      int byte = swz(row * 512 + kq * 16, row);
      size_t ga = ((size_t)b * TT + j0 + row) * 256 + kq * 8;
      *(f16x8*)((char*)Ph + byte) = *(const f16x8*)(ph_h + ga);
      *(f16x8*)((char*)Pl + byte) = *(const f16x8*)(ph_l + ga);
    }
    __syncthreads();
    // ---- QK^T with correction accumulator (theta_lo from L1 per use)
    f32x4 s4[2] = {(f32x4){0.f, 0.f, 0.f, 0.f}, (f32x4){0.f, 0.f, 0.f, 0.f}};
    f32x4 s4L[2] = {(f32x4){0.f, 0.f, 0.f, 0.f}, (f32x4){0.f, 0.f, 0.f, 0.f}};
#pragma unroll
    for (int kf = 0; kf < 8; ++kf) {
      f16x8 qlv = *(const f16x8*)(th_l + tbase + kf * 32);
#pragma unroll
      for (int jf = 0; jf < 2; ++jf) {
        int row = jf * 16 + (l & 15);
        int byte = swz(row * 512 + kf * 64 + ((l >> 4) << 4), row);
        f16x8 bh = *(const f16x8*)((char*)Ph + byte);
        f16x8 bl = *(const f16x8*)((char*)Pl + byte);
        s4[jf] = MFMA(qh[kf], bh, s4[jf]);
        s4L[jf] = MFMA(qlv, bh, s4L[jf]);
        s4L[jf] = MFMA(qh[kf], bl, s4L[jf]);
      }
    }
    // ---- online softmax (rows il of wave's 16)
#pragma unroll
    for (int r = 0; r < 4; ++r) {
      float sv0 = s4[0][r] + s4L[0][r] * INV2048;
      float sv1 = s4[1][r] + s4L[1][r] * INV2048;
      float mx = fmaxf(sv0, sv1);
#pragma unroll
      for (int sh = 8; sh >= 1; sh >>= 1) mx = fmaxf(mx, __shfl_xor(mx, sh));
      float mn = fmaxf(mrow[r], mx);
      float sc = __expf(mrow[r] - mn);
      mrow[r] = mn;
      float p0 = __expf(sv0 - mn);
      float p1 = __expf(sv1 - mn);
      float ls = p0 + p1;
#pragma unroll
      for (int sh = 8; sh >= 1; sh >>= 1) ls += __shfl_xor(ls, sh);
      lrow[r] = lrow[r] * sc + ls;
      int il = w * 16 + ((l >> 4) << 2) + r;
      int jj0 = (l & 15), jj1 = 16 + (l & 15);
      f16 h0 = (f16)p0, h1 = (f16)p1;
      *(f16*)((char*)sP + swz(il * 64 + jj0 * 2, il)) = h0;
      *(f16*)((char*)sP + swz(il * 64 + jj1 * 2, il)) = h1;
      *(f16*)((char*)sPl + swz(il * 64 + jj0 * 2, il)) =
          (f16)((p0 - (float)h0) * SC2048);
      *(f16*)((char*)sPl + swz(il * 64 + jj1 * 2, il)) =
          (f16)((p1 - (float)h1) * SC2048);
      if ((l & 15) == 0) sSc[il] = sc;
    }
    __syncthreads();  // P + sSc published; phi reads done
    // ---- stage g chunk [256 c'][32 j]
#pragma unroll
    for (int rep = 0; rep < 4; ++rep) {
      int slot = tid + rep * 256;
      int row = slot >> 2, kq = slot & 3;
      int byte = swz(row * 64 + kq * 16, row);
      size_t ga = ((size_t)b * 256 + row) * TT + j0 + kq * 8;
      *(f16x8*)((char*)Gh + byte) = *(const f16x8*)(g_h + ga);
      *(f16x8*)((char*)Gl + byte) = *(const f16x8*)(g_l + ga);
    }
    __syncthreads();
    // ---- rescale yacc/yaccL
#pragma unroll
    for (int mf = 0; mf < 4; ++mf)
#pragma unroll
      for (int r = 0; r < 4; ++r) {
        float s0 = sSc[mf * 16 + ((l >> 4) << 2) + r];
#pragma unroll
        for (int cf = 0; cf < 4; ++cf) {
          yacc[mf][cf][r] *= s0;
          yaccL[mf][cf][r] *= s0;
        }
      }
    // ---- PV: A=P rows (all 64 i), B=g (wave's 64 c'), 3-pass split
#pragma unroll
    for (int mp = 0; mp < 2; ++mp) {
      f16x8 pa[2], paL[2];
#pragma unroll
      for (int mi = 0; mi < 2; ++mi) {
        int row = (mp * 2 + mi) * 16 + (l & 15);
        int byte = swz(row * 64 + ((l >> 4) << 4), row);
        pa[mi] = *(const f16x8*)((char*)sP + byte);
        paL[mi] = *(const f16x8*)((char*)sPl + byte);
      }
#pragma unroll
      for (int cf = 0; cf < 4; ++cf) {
        int crow = w * 64 + cf * 16 + (l & 15);
        int byte = swz(crow * 64 + ((l >> 4) << 4), crow);
        f16x8 gh = *(const f16x8*)((char*)Gh + byte);
        f16x8 gl = *(const f16x8*)((char*)Gl + byte);
#pragma unroll
        for (int mi = 0; mi < 2; ++mi)
          yacc[mp * 2 + mi][cf] = MFMA(pa[mi], gh, yacc[mp * 2 + mi][cf]);
#pragma unroll
        for (int mi = 0; mi < 2; ++mi)
          yaccL[mp * 2 + mi][cf] = MFMA(paL[mi], gh, yaccL[mp * 2 + mi][cf]);
#pragma unroll
        for (int mi = 0; mi < 2; ++mi)
          yaccL[mp * 2 + mi][cf] = MFMA(pa[mi], gl, yaccL[mp * 2 + mi][cf]);
      }
    }
    __syncthreads();  // g/P reads done before next stage
  }

  // ---- write per-row (m,l) for this split
  if ((l & 15) == 0) {
#pragma unroll
    for (int r = 0; r < 4; ++r) {
      int row = w * 16 + ((l >> 4) << 2) + r;
      float2 v;
      v.x = mrow[r];
      v.y = lrow[r];
      ((float2*)mlb)[ks * 16384 + b * 2048 + i0 + row] = v;
    }
  }
  // ---- epilogue: UNNORMALIZED f32 partial via LDS transpose (2x32 rows)
  float* sOutF = (float*)U;
  float* ypb = yp + (size_t)ks * ((size_t)BB * TT * ICC);
  for (int c = 0; c < 2; ++c) {
#pragma unroll
    for (int mf2 = 0; mf2 < 2; ++mf2) {
      int mf = c * 2 + mf2;
#pragma unroll
      for (int r = 0; r < 4; ++r) {
        int row = mf * 16 + ((l >> 4) << 2) + r;
        int rl = row - c * 32;
#pragma unroll
        for (int cf = 0; cf < 4; ++cf)
          sOutF[rl * 264 + w * 64 + cf * 16 + (l & 15)] =
              yacc[mf][cf][r] + yaccL[mf][cf][r] * INV2048;
      }
    }
    __syncthreads();
    int row = tid >> 3, cc0 = (tid & 7) * 32;
    size_t ob = ((size_t)b * TT + i0 + c * 32 + row) * 256 + cc0;
#pragma unroll
    for (int e4 = 0; e4 < 8; ++e4) {
      float4 v;
      v.x = sOutF[row * 264 + cc0 + e4 * 4 + 0];
      v.y = sOutF[row * 264 + cc0 + e4 * 4 + 1];
      v.z = sOutF[row * 264 + cc0 + e4 * 4 + 2];
      v.w = sOutF[row * 264 + cc0 + e4 * 4 + 3];
      *(float4*)(ypb + ob + e4 * 4) = v;
    }
    __syncthreads();
  }
}

// ---------------------------------------------------------------------------
// Merge the two key-split partials: y = (e0*y0 + e1*y1)/(e0*l0 + e1*l1).
// ---------------------------------------------------------------------------
__global__ __launch_bounds__(256) void attn_merge(
    const float* __restrict__ yp, const float* __restrict__ mlb,
    f16* __restrict__ y_h, f16* __restrict__ y_l) {
  const size_t NP = (size_t)BB * TT * ICC;
  int gidx = blockIdx.x * 256 + threadIdx.x;  // 0..524287
  int rid = gidx >> 5;                        // row 0..16383 (b*2048+t)
  int c0 = (gidx & 31) * 8;
  const float2* ml2 = (const float2*)mlb;
  float2 a = ml2[rid];
  float2 bv = ml2[16384 + rid];
  float ms = fmaxf(a.x, bv.x);
  float e0 = __expf(a.x - ms), e1 = __expf(bv.x - ms);
  float inv = 1.f / (e0 * a.y + e1 * bv.y);
  e0 *= inv;
  e1 *= inv;
  size_t off = (size_t)rid * 256 + c0;
  f16 hv[8], lv[8];
#pragma unroll
  for (int e4 = 0; e4 < 2; ++e4) {
    float4 v0 = *(const float4*)(yp + off + e4 * 4);
    float4 v1 = *(const float4*)(yp + NP + off + e4 * 4);
    float vv[4] = {e0 * v0.x + e1 * v1.x, e0 * v0.y + e1 * v1.y,
                   e0 * v0.z + e1 * v1.z, e0 * v0.w + e1 * v1.w};
#pragma unroll
    for (int e = 0; e < 4; ++e) {
      f16 h = (f16)vv[e];
      hv[e4 * 4 + e] = h;
      lv[e4 * 4 + e] = (f16)((vv[e] - (float)h) * SC2048);
    }
  }
  *(f16x8*)&y_h[off] = *(f16x8*)hv;
  *(f16x8*)&y_l[off] = *(f16x8*)lv;
}

// ---------------------------------------------------------------------------
__global__ void zero_stats(double* s) { s[threadIdx.x] = 0.0; }

__global__ void bn_stats(const double* __restrict__ osum,
                         const double* __restrict__ osumsq,
                         float* __restrict__ mean, float* __restrict__ rstd) {
  int o = threadIdx.x;
  if (o < CC) {
    const double inv = 1.0 / (double)(BB * TT);
    double mu = osum[o] * inv;
    double var = osumsq[o] * inv - mu * mu;
    mean[o] = (float)mu;
    rstd[o] = (float)(1.0 / sqrt(var + (double)EPSV));
  }
}

__global__ __launch_bounds__(256) void bn_apply(
    float* __restrict__ out, const float* __restrict__ x,
    const float* __restrict__ mean, const float* __restrict__ rstd,
    const float* __restrict__ gamma, const float* __restrict__ beta) {
  const size_t n4 = (size_t)BB * CC * TT / 4;
  for (size_t idx = (size_t)blockIdx.x * blockDim.x + threadIdx.x; idx < n4;
       idx += (size_t)gridDim.x * blockDim.x) {
    size_t e = idx * 4;
    int o = (int)((e / TT) % CC);
    float4 wv = ((const float4*)out)[idx];
    float4 xv = ((const float4*)x)[idx];
    float mu = mean[o], rs = rstd[o], ga = gamma[o], be = beta[o];
    float4 r;
    r.x = fmaxf((wv.x - mu) * rs * ga + be, 0.f) + xv.x;
    r.y = fmaxf((wv.y - mu) * rs * ga + be, 0.f) + xv.y;
    r.z = fmaxf((wv.z - mu) * rs * ga + be, 0.f) + xv.z;
    r.w = fmaxf((wv.w - mu) * rs * ga + be, 0.f) + xv.w;
    ((float4*)out)[idx] = r;
  }
}

// ===========================================================================
// Fallback fp32 path (round-3, known-good) — used if ws too small.
// ===========================================================================
template <int M, int K, bool STATS>
__global__ __launch_bounds__(256) void gemm_proj(
    const float* __restrict__ W, const float* __restrict__ bias,
    const float* __restrict__ X, float* __restrict__ Out,
    double* __restrict__ osum, double* __restrict__ osumsq) {
  __shared__ float Ws[16][65];
  __shared__ float Xs[16][65];
  const int bt = blockIdx.x * 64, bm = blockIdx.y * 64, b = blockIdx.z;
  const int tid = threadIdx.x, tx = tid & 15, ty = tid >> 4;
  const float* Xb = X + (size_t)b * K * TT;
  float acc[4][4] = {};
  for (int kb = 0; kb < K; kb += 16) {
#pragma unroll
    for (int r = 0; r < 4; ++r) {
      int idx = tid + r * 256;
      int m = idx >> 4, k = idx & 15;
      Ws[k][m] = W[(size_t)(bm + m) * K + kb + k];
      int kx = idx >> 6, t = idx & 63;
      Xs[kx][t] = Xb[(size_t)(kb + kx) * TT + bt + t];
    }
    __syncthreads();
#pragma unroll
    for (int k = 0; k < 16; ++k) {
      float a[4], bv[4];
#pragma unroll
      for (int i = 0; i < 4; ++i) a[i] = Ws[k][ty * 4 + i];
#pragma unroll
      for (int j = 0; j < 4; ++j) bv[j] = Xs[k][tx * 4 + j];
#pragma unroll
      for (int i = 0; i < 4; ++i)
#pragma unroll
        for (int j = 0; j < 4; ++j) acc[i][j] += a[i] * bv[j];
    }
    __syncthreads();
  }
#pragma unroll
  for (int i = 0; i < 4; ++i) {
    int m = bm + ty * 4 + i;
    float bv = bias[m];
    double rs = 0.0, rq = 0.0;
#pragma unroll
    for (int j = 0; j < 4; ++j) {
      float v = acc[i][j] + bv;
      Out[((size_t)b * M + m) * TT + bt + tx * 4 + j] = v;
      if (STATS) {
        rs += (double)v;
        rq += (double)v * (double)v;
      }
    }
    if (STATS) {
#pragma unroll
      for (int s = 8; s >= 1; s >>= 1) {
        rs += __shfl_xor(rs, s, 16);
        rq += __shfl_xor(rq, s, 16);
      }
      if (tx == 0) {
        atomicAdd(&osum[m], rs);
        atomicAdd(&osumsq[m], rq);
      }
    }
  }
}

__global__ __launch_bounds__(256) void attn_flash(
    const float* __restrict__ th, const float* __restrict__ ph,
    const float* __restrict__ gx, float* __restrict__ y) {
  __shared__ float As[16][65];
  __shared__ float Bs[16][65];
  __shared__ float Ps[64][65];
  __shared__ float Gs[64][65];
  __shared__ float mScale[64];
  __shared__ float lArr[64];
  const int i0 = blockIdx.x * 64, b = blockIdx.y;
  const int tid = threadIdx.x, tx = tid & 15, ty = tid >> 4;
  const float* thb = th + (size_t)b * ICC * TT;
  const float* phb = ph + (size_t)b * ICC * TT;
  const float* gb = gx + (size_t)b * ICC * TT;
  float m[4], l[4];
#pragma unroll
  for (int i = 0; i < 4; ++i) {
    m[i] = -1e30f;
    l[i] = 0.f;
  }
  float acc[4][4][4] = {};
  for (int j0 = 0; j0 < TT; j0 += 64) {
    float S[4][4] = {};
    for (int cb = 0; cb < ICC; cb += 16) {
#pragma unroll
      for (int r = 0; r < 4; ++r) {
        int idx = tid + r * 256;
        int k = idx >> 6, col = idx & 63;
        As[k][col] = thb[(size_t)(cb + k) * TT + i0 + col];
        Bs[k][col] = phb[(size_t)(cb + k) * TT + j0 + col];
      }
      __syncthreads();
#pragma unroll
      for (int k = 0; k < 16; ++k) {
        float a[4], bv[4];
#pragma unroll
        for (int i = 0; i < 4; ++i) a[i] = As[k][ty * 4 + i];
#pragma unroll
        for (int j = 0; j < 4; ++j) bv[j] = Bs[k][tx * 4 + j];
#pragma unroll
        for (int i = 0; i < 4; ++i)
#pragma unroll
          for (int j = 0; j < 4; ++j) S[i][j] += a[i] * bv[j];
      }
      __syncthreads();
    }
    float sc[4];
#pragma unroll
    for (int i = 0; i < 4; ++i) {
      float mc = S[i][0];
#pragma unroll
      for (int j = 1; j < 4; ++j) mc = fmaxf(mc, S[i][j]);
#pragma unroll
      for (int s = 8; s >= 1; s >>= 1) mc = fmaxf(mc, __shfl_xor(mc, s, 16));
      float mn = fmaxf(m[i], mc);
      sc[i] = __expf(m[i] - mn);
      float lsum = 0.f;
#pragma unroll
      for (int j = 0; j < 4; ++j) {
        float p = __expf(S[i][j] - mn);
        S[i][j] = p;
        lsum += p;
      }
#pragma unroll
      for (int s = 8; s >= 1; s >>= 1) lsum += __shfl_xor(lsum, s, 16);
      l[i] = l[i] * sc[i] + lsum;
      m[i] = mn;
#pragma unroll
      for (int j = 0; j < 4; ++j) Ps[ty * 4 + i][tx * 4 + j] = S[i][j];
    }
    if (tx == 0) {
#pragma unroll
      for (int i = 0; i < 4; ++i) mScale[ty * 4 + i] = sc[i];
    }
    __syncthreads();
#pragma unroll
    for (int cq = 0; cq < 4; ++cq) {
#pragma unroll
      for (int r = 0; r < 16; ++r) {
        int idx = tid + r * 256;
        int cpr = idx >> 6, j = idx & 63;
        Gs[cpr][j] = gb[(size_t)(cq * 64 + cpr) * TT + j0 + j];
      }
      __syncthreads();
      float scj[4];
#pragma unroll
      for (int jq = 0; jq < 4; ++jq) scj[jq] = mScale[tx * 4 + jq];
#pragma unroll
      for (int ci = 0; ci < 4; ++ci)
#pragma unroll
        for (int jq = 0; jq < 4; ++jq) acc[cq][ci][jq] *= scj[jq];
      for (int j = 0; j < 64; ++j) {
        float a[4], p[4];
#pragma unroll
        for (int ci = 0; ci < 4; ++ci) a[ci] = Gs[ty * 4 + ci][j];
#pragma unroll
        for (int jq = 0; jq < 4; ++jq) p[jq] = Ps[tx * 4 + jq][j];
#pragma unroll
        for (int ci = 0; ci < 4; ++ci)
#pragma unroll
          for (int jq = 0; jq < 4; ++jq) acc[cq][ci][jq] += a[ci] * p[jq];
      }
      __syncthreads();
    }
  }
  if (tx == 0) {
#pragma unroll
    for (int i = 0; i < 4; ++i) lArr[ty * 4 + i] = l[i];
  }
  __syncthreads();
  float linv[4];
#pragma unroll
  for (int jq = 0; jq < 4; ++jq) linv[jq] = 1.f / lArr[tx * 4 + jq];
#pragma unroll
  for (int cq = 0; cq < 4; ++cq)
#pragma unroll
    for (int ci = 0; ci < 4; ++ci)
#pragma unroll
      for (int jq = 0; jq < 4; ++jq)
        y[((size_t)b * ICC + cq * 64 + ty * 4 + ci) * TT + i0 + tx * 4 + jq] =
            acc[cq][ci][jq] * linv[jq];
}

// ---------------------------------------------------------------------------
extern "C" void kernel_launch(void* const* d_in, const int* in_sizes, int n_in,
                              void* d_out, int out_size, void* d_ws,
                              size_t ws_size, hipStream_t stream) {
  const float* x = (const float*)d_in[0];
  const float* g_w = (const float*)d_in[1];
  const float* g_b = (const float*)d_in[2];
  const float* th_w = (const float*)d_in[3];
  const float* th_b = (const float*)d_in[4];
  const float* ph_w = (const float*)d_in[5];
  const float* ph_b = (const float*)d_in[6];
  const float* W_w = (const float*)d_in[7];
  const float* W_b = (const float*)d_in[8];
  const float* gamma = (const float*)d_in[9];
  const float* beta = (const float*)d_in[10];
  float* out = (float*)d_out;
  dim3 blk(256);

  const size_t NP = (size_t)BB * TT * ICC;  // 4,194,304
  const size_t NW = 131072;                 // 256*512
  const size_t need =
      (8 * NP + 8 * NW) * sizeof(f16) + 8192 + 4096 + 65536 * 4;

  if (ws_size >= need) {
    // ---------------- fast MFMA path ----------------
    f16* p = (f16*)d_ws;
    f16 *thH = p, *thL = thH + NP, *phH = thL + NP, *phL = phH + NP;
    f16 *gH = phL + NP, *gL = gH + NP, *yH = gL + NP, *yL = yH + NP;
    f16* wp = yL + NP;
    f16 *gwH = wp, *gwL = gwH + NW, *twH = gwL + NW, *twL = twH + NW;
    f16 *pwH = twL + NW, *pwL = pwH + NW, *wwH = pwL + NW, *wwL = wwH + NW;
    double* statd = (double*)(wwL + NW);
    float* meanb = (float*)(statd + 1024);
    float* rstdb = meanb + 512;
    float* mlbuf = rstdb + 512;  // 65536 floats: [2][8][2048]{m,l}
    f16* xTh = (f16*)d_out;  // xT hi/lo lives in d_out (dead before attn)
    f16* xTl = xTh + (size_t)BB * TT * CC;
    float* yp = (float*)d_out;  // attn partials reuse d_out (xT dead by then)

    split_transpose_x<<<dim3(TT / 32, CC / 32, BB), dim3(32, 8), 0, stream>>>(
        x, xTh, xTl);
    split_w<<<512, 256, 0, stream>>>(g_w, gwH, gwL, (int)NW);
    split_w<<<512, 256, 0, stream>>>(th_w, twH, twL, (int)NW);
    split_w<<<512, 256, 0, stream>>>(ph_w, pwH, pwL, (int)NW);
    split_w<<<512, 256, 0, stream>>>(W_w, wwH, wwL, (int)NW);
    zero_stats<<<1, 1024, 0, stream>>>(statd);

    // theta/phi: D[t][ic] = xT * W^T   (M=T, N=IC, K=C, bias on N)
    gemm_nt<TT, ICC, CC, true, false><<<dim3(2, 16, BB), blk, 0, stream>>>(
        xTh, xTl, (long)TT * CC, twH, twL, 0, th_b, thH, thL, nullptr,
        (long)TT * ICC, nullptr, nullptr);
    gemm_nt<TT, ICC, CC, true, false><<<dim3(2, 16, BB), blk, 0, stream>>>(
        xTh, xTl, (long)TT * CC, pwH, pwL, 0, ph_b, phH, phL, nullptr,
        (long)TT * ICC, nullptr, nullptr);
    // g: D[ic][t] = Wg * xT^T   (M=IC, N=T, K=C, bias on M)
    gemm_nt<ICC, TT, CC, false, false><<<dim3(16, 2, BB), blk, 0, stream>>>(
        gwH, gwL, 0, xTh, xTl, (long)TT * CC, g_b, gH, gL, nullptr,
        (long)ICC * TT, nullptr, nullptr);
    // attention: 512 blocks (2 key-splits), partials into d_out
    attn_mfma<<<512, blk, 0, stream>>>(thH, thL, phH, phL, gH, gL, yp, mlbuf);
    attn_merge<<<2048, blk, 0, stream>>>(yp, mlbuf, yH, yL);
    // W conv: D[o][t] -> d_out + BN stats  (M=C, N=T, K=IC, bias on M)
    gemm_nt<CC, TT, ICC, false, true><<<dim3(16, 4, BB), blk, 0, stream>>>(
        wwH, wwL, 0, yH, yL, (long)TT * ICC, W_b, nullptr, nullptr, out,
        (long)CC * TT, statd, statd + CC);
    bn_stats<<<1, 512, 0, stream>>>(statd, statd + CC, meanb, rstdb);
    bn_apply<<<2048, 256, 0, stream>>>(out, x, meanb, rstdb, gamma, beta);
  } else {
    // ---------------- fallback fp32 path ----------------
    float* ws = (float*)d_ws;
    const size_t np = (size_t)BB * ICC * TT;
    float* thb = ws;
    float* phb = ws + np;
    float* gbuf = ws + 2 * np;
    float* yb = thb;
    double* statd = (double*)(ws + 3 * np);
    float* meanb = (float*)(statd + 1024);
    float* rstdb = meanb + 512;
    gemm_proj<ICC, CC, false><<<dim3(TT / 64, ICC / 64, BB), blk, 0, stream>>>(
        th_w, th_b, x, thb, nullptr, nullptr);
    gemm_proj<ICC, CC, false><<<dim3(TT / 64, ICC / 64, BB), blk, 0, stream>>>(
        ph_w, ph_b, x, phb, nullptr, nullptr);
    gemm_proj<ICC, CC, false><<<dim3(TT / 64, ICC / 64, BB), blk, 0, stream>>>(
        g_w, g_b, x, gbuf, nullptr, nullptr);
    attn_flash<<<dim3(TT / 64, BB), blk, 0, stream>>>(thb, phb, gbuf, yb);
    zero_stats<<<1, 1024, 0, stream>>>(statd);
    gemm_proj<CC, ICC, true><<<dim3(TT / 64, CC / 64, BB), blk, 0, stream>>>(
        W_w, W_b, yb, out, statd, statd + CC);
    bn_stats<<<1, 512, 0, stream>>>(statd, statd + CC, meanb, rstdb);
    bn_apply<<<2048, 256, 0, stream>>>(out, x, meanb, rstdb, gamma, beta);
  }
}

// Round 12
// 470.498 us; speedup vs baseline: 1.5828x; 1.5828x over previous
//
#include <hip/hip_runtime.h>
#include <math.h>

#define BB 8
#define CC 512
#define TT 2048
#define ICC 256
#define EPSV 1e-5f
#define SC2048 2048.0f
#define INV2048 4.8828125e-4f

typedef _Float16 f16;
typedef __attribute__((ext_vector_type(8))) _Float16 f16x8;
typedef __attribute__((ext_vector_type(4))) float f32x4;

#define MFMA(a, b, c) __builtin_amdgcn_mfma_f32_16x16x32_f16(a, b, c, 0, 0, 0)

__device__ __forceinline__ int swz(int byte, int row) {
  return byte ^ ((row & 7) << 4);
}

// ---------------------------------------------------------------------------
// P0: x[b][c][t] f32 -> xT hi / scaled-lo f16 [b][t][c]
// ---------------------------------------------------------------------------
__global__ __launch_bounds__(256) void split_transpose_x(
    const float* __restrict__ x, f16* __restrict__ xh, f16* __restrict__ xl) {
  __shared__ float tile[32][33];
  const int tx = threadIdx.x, ty = threadIdx.y;
  const int t0 = blockIdx.x * 32, c0 = blockIdx.y * 32, b = blockIdx.z;
#pragma unroll
  for (int k = 0; k < 4; ++k)
    tile[ty + 8 * k][tx] = x[((size_t)b * CC + c0 + ty + 8 * k) * TT + t0 + tx];
  __syncthreads();
#pragma unroll
  for (int k = 0; k < 4; ++k) {
    float v = tile[tx][ty + 8 * k];
    size_t o = ((size_t)b * TT + t0 + ty + 8 * k) * CC + c0 + tx;
    f16 h = (f16)v;
    xh[o] = h;
    xl[o] = (f16)((v - (float)h) * SC2048);
  }
}

__global__ void split_w(const float* __restrict__ src, f16* __restrict__ h,
                        f16* __restrict__ lo, int n) {
  int i = blockIdx.x * 256 + threadIdx.x;
  if (i < n) {
    float v = src[i];
    f16 a = (f16)v;
    h[i] = a;
    lo[i] = (f16)((v - (float)a) * SC2048);
  }
}

// ---------------------------------------------------------------------------
// NT GEMM (verified): D = A*B^T + bias, split-f16.
// ---------------------------------------------------------------------------
template <int M, int N, int K, bool BIAS_N, bool F32OUT>
__global__ __launch_bounds__(256) void gemm_nt(
    const f16* __restrict__ Ah, const f16* __restrict__ Al, long strideA,
    const f16* __restrict__ Bh, const f16* __restrict__ Bl, long strideB,
    const float* __restrict__ bias, f16* __restrict__ Oh, f16* __restrict__ Ol,
    float* __restrict__ Of, long strideO, double* __restrict__ osum,
    double* __restrict__ osumsq) {
  __shared__ f16 sAh[4096], sAl[4096], sBh[4096], sBl[4096];
  __shared__ float sOut[F32OUT ? 1 : 32 * 132];
  const int tid = threadIdx.x;
  const int w = tid >> 6, l = tid & 63;
  const int bn = blockIdx.x * 128, bm = blockIdx.y * 128;
  const size_t baseA = (size_t)blockIdx.z * strideA;
  const size_t baseB = (size_t)blockIdx.z * strideB;
  const size_t baseO = (size_t)blockIdx.z * strideO;
  const int m0 = (w >> 1) * 64, n0 = (w & 1) * 64;
  char* cAh = (char*)sAh;
  char* cAl = (char*)sAl;
  char* cBh = (char*)sBh;
  char* cBl = (char*)sBl;

  f32x4 acc[4][4], accL[4][4];
#pragma unroll
  for (int i = 0; i < 4; ++i)
#pragma unroll
    for (int j = 0; j < 4; ++j) {
      acc[i][j] = (f32x4){0.f, 0.f, 0.f, 0.f};
      accL[i][j] = (f32x4){0.f, 0.f, 0.f, 0.f};
    }

  for (int kb = 0; kb < K; kb += 32) {
    __syncthreads();
#pragma unroll
    for (int rep = 0; rep < 2; ++rep) {
      int slot = tid + rep * 256;
      int row = slot >> 2, ks = slot & 3;
      int byte = swz(row * 64 + ks * 16, row);
      size_t ga = baseA + (size_t)(bm + row) * K + kb + ks * 8;
      size_t gb = baseB + (size_t)(bn + row) * K + kb + ks * 8;
      *(f16x8*)(cAh + byte) = *(const f16x8*)(Ah + ga);
      *(f16x8*)(cAl + byte) = *(const f16x8*)(Al + ga);
      *(f16x8*)(cBh + byte) = *(const f16x8*)(Bh + gb);
      *(f16x8*)(cBl + byte) = *(const f16x8*)(Bl + gb);
    }
    __syncthreads();
    f16x8 ah[4], al[4];
#pragma unroll
    for (int mf = 0; mf < 4; ++mf) {
      int row = m0 + mf * 16 + (l & 15);
      int byte = swz(row * 64 + ((l >> 4) << 4), row);
      ah[mf] = *(const f16x8*)(cAh + byte);
      al[mf] = *(const f16x8*)(cAl + byte);
    }
#pragma unroll
    for (int nf = 0; nf < 4; ++nf) {
      int row = n0 + nf * 16 + (l & 15);
      int byte = swz(row * 64 + ((l >> 4) << 4), row);
      f16x8 bh = *(const f16x8*)(cBh + byte);
      f16x8 bl = *(const f16x8*)(cBl + byte);
#pragma unroll
      for (int mf = 0; mf < 4; ++mf)
        acc[mf][nf] = MFMA(ah[mf], bh, acc[mf][nf]);
#pragma unroll
      for (int mf = 0; mf < 4; ++mf)
        accL[mf][nf] = MFMA(al[mf], bh, accL[mf][nf]);
#pragma unroll
      for (int mf = 0; mf < 4; ++mf)
        accL[mf][nf] = MFMA(ah[mf], bl, accL[mf][nf]);
    }
  }

  if (F32OUT) {
#pragma unroll
    for (int mf = 0; mf < 4; ++mf)
#pragma unroll
      for (int r = 0; r < 4; ++r) {
        int mrow = bm + m0 + mf * 16 + ((l >> 4) << 2) + r;
        float bv = bias[mrow];
        double s = 0.0, q = 0.0;
#pragma unroll
        for (int nf = 0; nf < 4; ++nf) {
          float v = acc[mf][nf][r] + accL[mf][nf][r] * INV2048 + bv;
          Of[baseO + (size_t)mrow * N + bn + n0 + nf * 16 + (l & 15)] = v;
          s += (double)v;
          q += (double)v * (double)v;
        }
#pragma unroll
        for (int sh = 8; sh >= 1; sh >>= 1) {
          s += __shfl_xor(s, sh);
          q += __shfl_xor(q, sh);
        }
        if ((l & 15) == 0) {
          atomicAdd(&osum[mrow], s);
          atomicAdd(&osumsq[mrow], q);
        }
      }
  } else {
    for (int c = 0; c < 4; ++c) {
      __syncthreads();
      if ((w >> 1) == (c >> 1)) {
#pragma unroll
        for (int mf2 = 0; mf2 < 2; ++mf2) {
          int mf = (c & 1) * 2 + mf2;
          int rl = m0 - c * 32 + mf * 16 + ((l >> 4) << 2);
#pragma unroll
          for (int nf = 0; nf < 4; ++nf)
#pragma unroll
            for (int r = 0; r < 4; ++r)
              sOut[(rl + r) * 132 + n0 + nf * 16 + (l & 15)] =
                  acc[mf][nf][r] + accL[mf][nf][r] * INV2048;
        }
      }
      __syncthreads();
      int row = tid >> 3, cc0 = (tid & 7) * 16;
      size_t gm = bm + c * 32 + row;
      size_t ob = baseO + gm * (size_t)N + bn + cc0;
      f16 hv[16], lv[16];
#pragma unroll
      for (int e = 0; e < 16; ++e) {
        float v = sOut[row * 132 + cc0 + e];
        v += BIAS_N ? bias[bn + cc0 + e] : bias[gm];
        f16 h = (f16)v;
        hv[e] = h;
        lv[e] = (f16)((v - (float)h) * SC2048);
      }
      *(f16x8*)&Oh[ob] = *(f16x8*)hv;
      *(f16x8*)&Oh[ob + 8] = *(f16x8*)(hv + 8);
      *(f16x8*)&Ol[ob] = *(f16x8*)lv;
      *(f16x8*)&Ol[ob + 8] = *(f16x8*)(lv + 8);
    }
  }
}

// ---------------------------------------------------------------------------
// Fused flash attention v5 (r12): 8-wave block, accumulator halved.
// grid 256 = q-tile(5b)|b(3b), block 512 thr = 8 waves = 2 waves/SIMD.
//  - QK^T: K-split across wave halves. Wave w: rows (w&3)*16..+16, channels
//    gq*128..+128 (gq=w>>2). Partial S (with lo-corrections folded) written
//    to sS[gq][64][33] f32; softmax sums the two planes.
//  - softmax: wave w owns rows w*8..+8; 32-lane j-reduction.
//  - PV: wave w owns channels w*32..+32 -> yacc[4][2]+yaccL[4][2] = 64 regs
//    (vs 128 in r6-r11 -> fits 2 waves/EU's 256-reg budget without spill).
//  - amdgpu_waves_per_eu(2,2) pins the allocator to the 256-reg budget
//    (launch_bounds min-waves alone let the heuristic pick 128 and spill).
// ---------------------------------------------------------------------------
__global__ __launch_bounds__(512)
    __attribute__((amdgpu_waves_per_eu(2, 2))) void attn_mfma(
        const f16* __restrict__ th_h, const f16* __restrict__ th_l,
        const f16* __restrict__ ph_h, const f16* __restrict__ ph_l,
        const f16* __restrict__ g_h, const f16* __restrict__ g_l,
        f16* __restrict__ y_h, f16* __restrict__ y_l) {
  __shared__ f16 sPhiH[8192], sPhiL[8192];  // phi [32 j][256 c] swizzled
  __shared__ f16 sGH[8192], sGL[8192];      // g   [256 c][32 j] swizzled
  __shared__ float sS[2][64][33];           // combined partial S per K-half
  __shared__ f16 sP[2048], sPl[2048];       // P hi / scaled-lo [64][32]
  __shared__ float sSc[64], sL[64];
  const int tid = threadIdx.x, w = tid >> 6, l = tid & 63;
  const int b = blockIdx.x & 7;
  const int i0 = (blockIdx.x >> 3) * 64;
  const int gq = w >> 2;       // K-half for QK
  const int rw = (w & 3) * 16; // QK row base

  // theta fragments (wave's 16 rows x its 128-channel half)
  const size_t tbase =
      ((size_t)b * TT + i0 + rw + (l & 15)) * 256 + gq * 128 + ((l >> 4) << 3);
  f16x8 qh[4], ql[4];
#pragma unroll
  for (int kf = 0; kf < 4; ++kf) {
    qh[kf] = *(const f16x8*)(th_h + tbase + kf * 32);
    ql[kf] = *(const f16x8*)(th_l + tbase + kf * 32);
  }
  f32x4 yacc[4][2], yaccL[4][2];
#pragma unroll
  for (int i = 0; i < 4; ++i)
#pragma unroll
    for (int j = 0; j < 2; ++j) {
      yacc[i][j] = (f32x4){0.f, 0.f, 0.f, 0.f};
      yaccL[i][j] = (f32x4){0.f, 0.f, 0.f, 0.f};
    }
  float mrow[4], lrow[4];  // softmax rows w*8 + (l>>5)*4 + ry
#pragma unroll
  for (int r = 0; r < 4; ++r) {
    mrow[r] = -3e38f;
    lrow[r] = 0.f;
  }

  for (int jc = 0; jc < 64; ++jc) {
    const int j0 = jc * 32;
    // ---- stage phi [32 j][256 c]: 1024 f16x8 slots, 512 thr x 2 reps
#pragma unroll
    for (int rep = 0; rep < 2; ++rep) {
      int slot = tid + rep * 512;
      int row = slot >> 5, kq = slot & 31;
      int byte = swz(row * 512 + kq * 16, row);
      size_t ga = ((size_t)b * TT + j0 + row) * 256 + kq * 8;
      *(f16x8*)((char*)sPhiH + byte) = *(const f16x8*)(ph_h + ga);
      *(f16x8*)((char*)sPhiL + byte) = *(const f16x8*)(ph_l + ga);
    }
    // ---- stage g [256 c][32 j]
#pragma unroll
    for (int rep = 0; rep < 2; ++rep) {
      int slot = tid + rep * 512;
      int row = slot >> 2, kq = slot & 3;
      int byte = swz(row * 64 + kq * 16, row);
      size_t ga = ((size_t)b * 256 + row) * TT + j0 + kq * 8;
      *(f16x8*)((char*)sGH + byte) = *(const f16x8*)(g_h + ga);
      *(f16x8*)((char*)sGL + byte) = *(const f16x8*)(g_l + ga);
    }
    __syncthreads();  // A: tiles staged
    // ---- QK^T partial over this wave's 128-channel half
    f32x4 s4[2] = {(f32x4){0.f, 0.f, 0.f, 0.f}, (f32x4){0.f, 0.f, 0.f, 0.f}};
    f32x4 s4L[2] = {(f32x4){0.f, 0.f, 0.f, 0.f}, (f32x4){0.f, 0.f, 0.f, 0.f}};
#pragma unroll
    for (int kf = 0; kf < 4; ++kf) {
#pragma unroll
      for (int jf = 0; jf < 2; ++jf) {
        int prow = jf * 16 + (l & 15);
        int byte =
            swz(prow * 512 + gq * 256 + kf * 64 + ((l >> 4) << 4), prow);
        f16x8 bh = *(const f16x8*)((char*)sPhiH + byte);
        f16x8 bl = *(const f16x8*)((char*)sPhiL + byte);
        s4[jf] = MFMA(qh[kf], bh, s4[jf]);
        s4L[jf] = MFMA(ql[kf], bh, s4L[jf]);
        s4L[jf] = MFMA(qh[kf], bl, s4L[jf]);
      }
    }
    // write combined partial (corrections folded) to sS[gq]
#pragma unroll
    for (int jf = 0; jf < 2; ++jf)
#pragma unroll
      for (int r = 0; r < 4; ++r) {
        int row = rw + ((l >> 4) << 2) + r;
        sS[gq][row][jf * 16 + (l & 15)] = s4[jf][r] + s4L[jf][r] * INV2048;
      }
    __syncthreads();  // B: S complete
    // ---- softmax: wave owns rows w*8..w*8+8; lane jcol=l&31, half=l>>5
    {
      int jcol = l & 31;
#pragma unroll
      for (int ry = 0; ry < 4; ++ry) {
        int row = w * 8 + (l >> 5) * 4 + ry;
        float sv = sS[0][row][jcol] + sS[1][row][jcol];
        float mx = sv;
#pragma unroll
        for (int sh = 16; sh >= 1; sh >>= 1) mx = fmaxf(mx, __shfl_xor(mx, sh));
        float mn = fmaxf(mrow[ry], mx);
        float sc = __expf(mrow[ry] - mn);
        mrow[ry] = mn;
        float p = __expf(sv - mn);
        float ls = p;
#pragma unroll
        for (int sh = 16; sh >= 1; sh >>= 1) ls += __shfl_xor(ls, sh);
        lrow[ry] = lrow[ry] * sc + ls;
        f16 h = (f16)p;
        *(f16*)((char*)sP + swz(row * 64 + jcol * 2, row)) = h;
        *(f16*)((char*)sPl + swz(row * 64 + jcol * 2, row)) =
            (f16)((p - (float)h) * SC2048);
        if (jcol == 0) sSc[row] = sc;
      }
    }
    __syncthreads();  // C: P + sSc published
    // ---- rescale accumulators
#pragma unroll
    for (int mf = 0; mf < 4; ++mf)
#pragma unroll
      for (int r = 0; r < 4; ++r) {
        float s0 = sSc[mf * 16 + ((l >> 4) << 2) + r];
#pragma unroll
        for (int cf = 0; cf < 2; ++cf) {
          yacc[mf][cf][r] *= s0;
          yaccL[mf][cf][r] *= s0;
        }
      }
    // ---- PV: A=P (all 64 rows), B=g (wave's 32 channels), 3-pass
#pragma unroll
    for (int mf = 0; mf < 4; ++mf) {
      int prow = mf * 16 + (l & 15);
      int pb = swz(prow * 64 + ((l >> 4) << 4), prow);
      f16x8 pa = *(const f16x8*)((char*)sP + pb);
      f16x8 paL = *(const f16x8*)((char*)sPl + pb);
#pragma unroll
      for (int cf = 0; cf < 2; ++cf) {
        int crow = w * 32 + cf * 16 + (l & 15);
        int gb2 = swz(crow * 64 + ((l >> 4) << 4), crow);
        f16x8 gh = *(const f16x8*)((char*)sGH + gb2);
        f16x8 gl = *(const f16x8*)((char*)sGL + gb2);
        yacc[mf][cf] = MFMA(pa, gh, yacc[mf][cf]);
        yaccL[mf][cf] = MFMA(paL, gh, yaccL[mf][cf]);
        yaccL[mf][cf] = MFMA(pa, gl, yaccL[mf][cf]);
      }
    }
    __syncthreads();  // D: P/g reads done before next staging
  }

  // ---- publish final l per row
  if ((l & 31) == 0) {
#pragma unroll
    for (int ry = 0; ry < 4; ++ry) sL[w * 8 + (l >> 5) * 4 + ry] = lrow[ry];
  }
  __syncthreads();
  // ---- epilogue: normalized y via f32 LDS transpose, 4 chunks of 16 rows
  float* sOutF = (float*)sPhiH;  // 32KB scratch (phi region dead)
  for (int c2 = 0; c2 < 4; ++c2) {
#pragma unroll
    for (int r = 0; r < 4; ++r) {
      int row = c2 * 16 + ((l >> 4) << 2) + r;
      float linv = 1.f / sL[row];
      int rl = row - c2 * 16;
#pragma unroll
      for (int cf = 0; cf < 2; ++cf)
        sOutF[rl * 264 + w * 32 + cf * 16 + (l & 15)] =
            (yacc[c2][cf][r] + yaccL[c2][cf][r] * INV2048) * linv;
    }
    __syncthreads();
    int row = tid >> 5, cc0 = (tid & 31) * 8;
    size_t ob = ((size_t)b * TT + i0 + c2 * 16 + row) * 256 + cc0;
    f16 hv[8], lv[8];
#pragma unroll
    for (int e = 0; e < 8; ++e) {
      float v = sOutF[row * 264 + cc0 + e];
      f16 h = (f16)v;
      hv[e] = h;
      lv[e] = (f16)((v - (float)h) * SC2048);
    }
    *(f16x8*)&y_h[ob] = *(f16x8*)hv;
    *(f16x8*)&y_l[ob] = *(f16x8*)lv;
    __syncthreads();
  }
}

// ---------------------------------------------------------------------------
__global__ void zero_stats(double* s) { s[threadIdx.x] = 0.0; }

__global__ void bn_stats(const double* __restrict__ osum,
                         const double* __restrict__ osumsq,
                         float* __restrict__ mean, float* __restrict__ rstd) {
  int o = threadIdx.x;
  if (o < CC) {
    const double inv = 1.0 / (double)(BB * TT);
    double mu = osum[o] * inv;
    double var = osumsq[o] * inv - mu * mu;
    mean[o] = (float)mu;
    rstd[o] = (float)(1.0 / sqrt(var + (double)EPSV));
  }
}

__global__ __launch_bounds__(256) void bn_apply(
    float* __restrict__ out, const float* __restrict__ x,
    const float* __restrict__ mean, const float* __restrict__ rstd,
    const float* __restrict__ gamma, const float* __restrict__ beta) {
  const size_t n4 = (size_t)BB * CC * TT / 4;
  for (size_t idx = (size_t)blockIdx.x * blockDim.x + threadIdx.x; idx < n4;
       idx += (size_t)gridDim.x * blockDim.x) {
    size_t e = idx * 4;
    int o = (int)((e / TT) % CC);
    float4 wv = ((const float4*)out)[idx];
    float4 xv = ((const float4*)x)[idx];
    float mu = mean[o], rs = rstd[o], ga = gamma[o], be = beta[o];
    float4 r;
    r.x = fmaxf((wv.x - mu) * rs * ga + be, 0.f) + xv.x;
    r.y = fmaxf((wv.y - mu) * rs * ga + be, 0.f) + xv.y;
    r.z = fmaxf((wv.z - mu) * rs * ga + be, 0.f) + xv.z;
    r.w = fmaxf((wv.w - mu) * rs * ga + be, 0.f) + xv.w;
    ((float4*)out)[idx] = r;
  }
}

// ===========================================================================
// Fallback fp32 path (round-3, known-good) — used if ws too small.
// ===========================================================================
template <int M, int K, bool STATS>
__global__ __launch_bounds__(256) void gemm_proj(
    const float* __restrict__ W, const float* __restrict__ bias,
    const float* __restrict__ X, float* __restrict__ Out,
    double* __restrict__ osum, double* __restrict__ osumsq) {
  __shared__ float Ws[16][65];
  __shared__ float Xs[16][65];
  const int bt = blockIdx.x * 64, bm = blockIdx.y * 64, b = blockIdx.z;
  const int tid = threadIdx.x, tx = tid & 15, ty = tid >> 4;
  const float* Xb = X + (size_t)b * K * TT;
  float acc[4][4] = {};
  for (int kb = 0; kb < K; kb += 16) {
#pragma unroll
    for (int r = 0; r < 4; ++r) {
      int idx = tid + r * 256;
      int m = idx >> 4, k = idx & 15;
      Ws[k][m] = W[(size_t)(bm + m) * K + kb + k];
      int kx = idx >> 6, t = idx & 63;
      Xs[kx][t] = Xb[(size_t)(kb + kx) * TT + bt + t];
    }
    __syncthreads();
#pragma unroll
    for (int k = 0; k < 16; ++k) {
      float a[4], bv[4];
#pragma unroll
      for (int i = 0; i < 4; ++i) a[i] = Ws[k][ty * 4 + i];
#pragma unroll
      for (int j = 0; j < 4; ++j) bv[j] = Xs[k][tx * 4 + j];
#pragma unroll
      for (int i = 0; i < 4; ++i)
#pragma unroll
        for (int j = 0; j < 4; ++j) acc[i][j] += a[i] * bv[j];
    }
    __syncthreads();
  }
#pragma unroll
  for (int i = 0; i < 4; ++i) {
    int m = bm + ty * 4 + i;
    float bv = bias[m];
    double rs = 0.0, rq = 0.0;
#pragma unroll
    for (int j = 0; j < 4; ++j) {
      float v = acc[i][j] + bv;
      Out[((size_t)b * M + m) * TT + bt + tx * 4 + j] = v;
      if (STATS) {
        rs += (double)v;
        rq += (double)v * (double)v;
      }
    }
    if (STATS) {
#pragma unroll
      for (int s = 8; s >= 1; s >>= 1) {
        rs += __shfl_xor(rs, s, 16);
        rq += __shfl_xor(rq, s, 16);
      }
      if (tx == 0) {
        atomicAdd(&osum[m], rs);
        atomicAdd(&osumsq[m], rq);
      }
    }
  }
}

__global__ __launch_bounds__(256) void attn_flash(
    const float* __restrict__ th, const float* __restrict__ ph,
    const float* __restrict__ gx, float* __restrict__ y) {
  __shared__ float As[16][65];
  __shared__ float Bs[16][65];
  __shared__ float Ps[64][65];
  __shared__ float Gs[64][65];
  __shared__ float mScale[64];
  __shared__ float lArr[64];
  const int i0 = blockIdx.x * 64, b = blockIdx.y;
  const int tid = threadIdx.x, tx = tid & 15, ty = tid >> 4;
  const float* thb = th + (size_t)b * ICC * TT;
  const float* phb = ph + (size_t)b * ICC * TT;
  const float* gb = gx + (size_t)b * ICC * TT;
  float m[4], l[4];
#pragma unroll
  for (int i = 0; i < 4; ++i) {
    m[i] = -1e30f;
    l[i] = 0.f;
  }
  float acc[4][4][4] = {};
  for (int j0 = 0; j0 < TT; j0 += 64) {
    float S[4][4] = {};
    for (int cb = 0; cb < ICC; cb += 16) {
#pragma unroll
      for (int r = 0; r < 4; ++r) {
        int idx = tid + r * 256;
        int k = idx >> 6, col = idx & 63;
        As[k][col] = thb[(size_t)(cb + k) * TT + i0 + col];
        Bs[k][col] = phb[(size_t)(cb + k) * TT + j0 + col];
      }
      __syncthreads();
#pragma unroll
      for (int k = 0; k < 16; ++k) {
        float a[4], bv[4];
#pragma unroll
        for (int i = 0; i < 4; ++i) a[i] = As[k][ty * 4 + i];
#pragma unroll
        for (int j = 0; j < 4; ++j) bv[j] = Bs[k][tx * 4 + j];
#pragma unroll
        for (int i = 0; i < 4; ++i)
#pragma unroll
          for (int j = 0; j < 4; ++j) S[i][j] += a[i] * bv[j];
      }
      __syncthreads();
    }
    float sc[4];
#pragma unroll
    for (int i = 0; i < 4; ++i) {
      float mc = S[i][0];
#pragma unroll
      for (int j = 1; j < 4; ++j) mc = fmaxf(mc, S[i][j]);
#pragma unroll
      for (int s = 8; s >= 1; s >>= 1) mc = fmaxf(mc, __shfl_xor(mc, s, 16));
      float mn = fmaxf(m[i], mc);
      sc[i] = __expf(m[i] - mn);
      float lsum = 0.f;
#pragma unroll
      for (int j = 0; j < 4; ++j) {
        float p = __expf(S[i][j] - mn);
        S[i][j] = p;
        lsum += p;
      }
#pragma unroll
      for (int s = 8; s >= 1; s >>= 1) lsum += __shfl_xor(lsum, s, 16);
      l[i] = l[i] * sc[i] + lsum;
      m[i] = mn;
#pragma unroll
      for (int j = 0; j < 4; ++j) Ps[ty * 4 + i][tx * 4 + j] = S[i][j];
    }
    if (tx == 0) {
#pragma unroll
      for (int i = 0; i < 4; ++i) mScale[ty * 4 + i] = sc[i];
    }
    __syncthreads();
#pragma unroll
    for (int cq = 0; cq < 4; ++cq) {
#pragma unroll
      for (int r = 0; r < 16; ++r) {
        int idx = tid + r * 256;
        int cpr = idx >> 6, j = idx & 63;
        Gs[cpr][j] = gb[(size_t)(cq * 64 + cpr) * TT + j0 + j];
      }
      __syncthreads();
      float scj[4];
#pragma unroll
      for (int jq = 0; jq < 4; ++jq) scj[jq] = mScale[tx * 4 + jq];
#pragma unroll
      for (int ci = 0; ci < 4; ++ci)
#pragma unroll
        for (int jq = 0; jq < 4; ++jq) acc[cq][ci][jq] *= scj[jq];
      for (int j = 0; j < 64; ++j) {
        float a[4], p[4];
#pragma unroll
        for (int ci = 0; ci < 4; ++ci) a[ci] = Gs[ty * 4 + ci][j];
#pragma unroll
        for (int jq = 0; jq < 4; ++jq) p[jq] = Ps[tx * 4 + jq][j];
#pragma unroll
        for (int ci = 0; ci < 4; ++ci)
#pragma unroll
          for (int jq = 0; jq < 4; ++jq) acc[cq][ci][jq] += a[ci] * p[jq];
      }
      __syncthreads();
    }
  }
  if (tx == 0) {
#pragma unroll
    for (int i = 0; i < 4; ++i) lArr[ty * 4 + i] = l[i];
  }
  __syncthreads();
  float linv[4];
#pragma unroll
  for (int jq = 0; jq < 4; ++jq) linv[jq] = 1.f / lArr[tx * 4 + jq];
#pragma unroll
  for (int cq = 0; cq < 4; ++cq)
#pragma unroll
    for (int ci = 0; ci < 4; ++ci)
#pragma unroll
      for (int jq = 0; jq < 4; ++jq)
        y[((size_t)b * ICC + cq * 64 + ty * 4 + ci) * TT + i0 + tx * 4 + jq] =
            acc[cq][ci][jq] * linv[jq];
}

// ---------------------------------------------------------------------------
extern "C" void kernel_launch(void* const* d_in, const int* in_sizes, int n_in,
                              void* d_out, int out_size, void* d_ws,
                              size_t ws_size, hipStream_t stream) {
  const float* x = (const float*)d_in[0];
  const float* g_w = (const float*)d_in[1];
  const float* g_b = (const float*)d_in[2];
  const float* th_w = (const float*)d_in[3];
  const float* th_b = (const float*)d_in[4];
  const float* ph_w = (const float*)d_in[5];
  const float* ph_b = (const float*)d_in[6];
  const float* W_w = (const float*)d_in[7];
  const float* W_b = (const float*)d_in[8];
  const float* gamma = (const float*)d_in[9];
  const float* beta = (const float*)d_in[10];
  float* out = (float*)d_out;
  dim3 blk(256);

  const size_t NP = (size_t)BB * TT * ICC;  // 4,194,304
  const size_t NW = 131072;                 // 256*512
  const size_t need = (8 * NP + 8 * NW) * sizeof(f16) + 8192 + 4096;

  if (ws_size >= need) {
    // ---------------- fast MFMA path ----------------
    f16* p = (f16*)d_ws;
    f16 *thH = p, *thL = thH + NP, *phH = thL + NP, *phL = phH + NP;
    f16 *gH = phL + NP, *gL = gH + NP, *yH = gL + NP, *yL = yH + NP;
    f16* wp = yL + NP;
    f16 *gwH = wp, *gwL = gwH + NW, *twH = gwL + NW, *twL = twH + NW;
    f16 *pwH = twL + NW, *pwL = pwH + NW, *wwH = pwL + NW, *wwL = wwH + NW;
    double* statd = (double*)(wwL + NW);
    float* meanb = (float*)(statd + 1024);
    float* rstdb = meanb + 512;
    f16* xTh = (f16*)d_out;  // xT hi/lo lives in d_out (dead before W-conv)
    f16* xTl = xTh + (size_t)BB * TT * CC;

    split_transpose_x<<<dim3(TT / 32, CC / 32, BB), dim3(32, 8), 0, stream>>>(
        x, xTh, xTl);
    split_w<<<512, 256, 0, stream>>>(g_w, gwH, gwL, (int)NW);
    split_w<<<512, 256, 0, stream>>>(th_w, twH, twL, (int)NW);
    split_w<<<512, 256, 0, stream>>>(ph_w, pwH, pwL, (int)NW);
    split_w<<<512, 256, 0, stream>>>(W_w, wwH, wwL, (int)NW);
    zero_stats<<<1, 1024, 0, stream>>>(statd);

    // theta/phi: D[t][ic] = xT * W^T   (M=T, N=IC, K=C, bias on N)
    gemm_nt<TT, ICC, CC, true, false><<<dim3(2, 16, BB), blk, 0, stream>>>(
        xTh, xTl, (long)TT * CC, twH, twL, 0, th_b, thH, thL, nullptr,
        (long)TT * ICC, nullptr, nullptr);
    gemm_nt<TT, ICC, CC, true, false><<<dim3(2, 16, BB), blk, 0, stream>>>(
        xTh, xTl, (long)TT * CC, pwH, pwL, 0, ph_b, phH, phL, nullptr,
        (long)TT * ICC, nullptr, nullptr);
    // g: D[ic][t] = Wg * xT^T   (M=IC, N=T, K=C, bias on M)
    gemm_nt<ICC, TT, CC, false, false><<<dim3(16, 2, BB), blk, 0, stream>>>(
        gwH, gwL, 0, xTh, xTl, (long)TT * CC, g_b, gH, gL, nullptr,
        (long)ICC * TT, nullptr, nullptr);
    // attention -> y f16 hi/lo directly (8-wave blocks, no merge)
    attn_mfma<<<256, dim3(512), 0, stream>>>(thH, thL, phH, phL, gH, gL, yH,
                                             yL);
    // W conv: D[o][t] -> d_out + BN stats  (M=C, N=T, K=IC, bias on M)
    gemm_nt<CC, TT, ICC, false, true><<<dim3(16, 4, BB), blk, 0, stream>>>(
        wwH, wwL, 0, yH, yL, (long)TT * ICC, W_b, nullptr, nullptr, out,
        (long)CC * TT, statd, statd + CC);
    bn_stats<<<1, 512, 0, stream>>>(statd, statd + CC, meanb, rstdb);
    bn_apply<<<2048, 256, 0, stream>>>(out, x, meanb, rstdb, gamma, beta);
  } else {
    // ---------------- fallback fp32 path ----------------
    float* ws = (float*)d_ws;
    const size_t np = (size_t)BB * ICC * TT;
    float* thb = ws;
    float* phb = ws + np;
    float* gbuf = ws + 2 * np;
    float* yb = thb;
    double* statd = (double*)(ws + 3 * np);
    float* meanb = (float*)(statd + 1024);
    float* rstdb = meanb + 512;
    gemm_proj<ICC, CC, false><<<dim3(TT / 64, ICC / 64, BB), blk, 0, stream>>>(
        th_w, th_b, x, thb, nullptr, nullptr);
    gemm_proj<ICC, CC, false><<<dim3(TT / 64, ICC / 64, BB), blk, 0, stream>>>(
        ph_w, ph_b, x, phb, nullptr, nullptr);
    gemm_proj<ICC, CC, false><<<dim3(TT / 64, ICC / 64, BB), blk, 0, stream>>>(
        g_w, g_b, x, gbuf, nullptr, nullptr);
    attn_flash<<<dim3(TT / 64, BB), blk, 0, stream>>>(thb, phb, gbuf, yb);
    zero_stats<<<1, 1024, 0, stream>>>(statd);
    gemm_proj<CC, ICC, true><<<dim3(TT / 64, CC / 64, BB), blk, 0, stream>>>(
        W_w, W_b, yb, out, statd, statd + CC);
    bn_stats<<<1, 512, 0, stream>>>(statd, statd + CC, meanb, rstdb);
    bn_apply<<<2048, 256, 0, stream>>>(out, x, meanb, rstdb, gamma, beta);
  }
}

// Round 13
// 464.065 us; speedup vs baseline: 1.6047x; 1.0139x over previous
//
#include <hip/hip_runtime.h>
#include <math.h>

#define BB 8
#define CC 512
#define TT 2048
#define ICC 256
#define EPSV 1e-5f
#define SC2048 2048.0f
#define INV2048 4.8828125e-4f

typedef _Float16 f16;
typedef __attribute__((ext_vector_type(8))) _Float16 f16x8;
typedef __attribute__((ext_vector_type(4))) float f32x4;

#define MFMA(a, b, c) __builtin_amdgcn_mfma_f32_16x16x32_f16(a, b, c, 0, 0, 0)

__device__ __forceinline__ int swz(int byte, int row) {
  return byte ^ ((row & 7) << 4);
}

// global -> LDS direct (16B/lane). LDS dest = wave-uniform base + lane*16.
__device__ __forceinline__ void ld_lds16(const void* g, void* l) {
  __builtin_amdgcn_global_load_lds(
      (const __attribute__((address_space(1))) unsigned int*)g,
      (__attribute__((address_space(3))) unsigned int*)l, 16, 0, 0);
}

// inverse of slot-swizzle o = s ^ ((s>>2)&7)  (row = slot>>2 layouts)
__device__ __forceinline__ int inv_swz_r2(int o) {
  return o ^ (((o >> 2) & 6) | (((o >> 2) ^ (o >> 4)) & 1));
}
// inverse of slot-swizzle o = s ^ ((s>>5)&7)  (row = slot>>5 layouts; involution)
__device__ __forceinline__ int inv_swz_r5(int o) { return o ^ ((o >> 5) & 7); }

// ---------------------------------------------------------------------------
// P0: x[b][c][t] f32 -> xT hi / scaled-lo f16 [b][t][c]
// ---------------------------------------------------------------------------
__global__ __launch_bounds__(256) void split_transpose_x(
    const float* __restrict__ x, f16* __restrict__ xh, f16* __restrict__ xl) {
  __shared__ float tile[32][33];
  const int tx = threadIdx.x, ty = threadIdx.y;
  const int t0 = blockIdx.x * 32, c0 = blockIdx.y * 32, b = blockIdx.z;
#pragma unroll
  for (int k = 0; k < 4; ++k)
    tile[ty + 8 * k][tx] = x[((size_t)b * CC + c0 + ty + 8 * k) * TT + t0 + tx];
  __syncthreads();
#pragma unroll
  for (int k = 0; k < 4; ++k) {
    float v = tile[tx][ty + 8 * k];
    size_t o = ((size_t)b * TT + t0 + ty + 8 * k) * CC + c0 + tx;
    f16 h = (f16)v;
    xh[o] = h;
    xl[o] = (f16)((v - (float)h) * SC2048);
  }
}

__global__ void split_w(const float* __restrict__ src, f16* __restrict__ h,
                        f16* __restrict__ lo, int n) {
  int i = blockIdx.x * 256 + threadIdx.x;
  if (i < n) {
    float v = src[i];
    f16 a = (f16)v;
    h[i] = a;
    lo[i] = (f16)((v - (float)a) * SC2048);
  }
}

// ---------------------------------------------------------------------------
// NT GEMM (verified layout): D = A*B^T + bias, split-f16.
// r13: staging via global_load_lds with pre-swizzled source slots.
// ---------------------------------------------------------------------------
template <int M, int N, int K, bool BIAS_N, bool F32OUT>
__global__ __launch_bounds__(256) void gemm_nt(
    const f16* __restrict__ Ah, const f16* __restrict__ Al, long strideA,
    const f16* __restrict__ Bh, const f16* __restrict__ Bl, long strideB,
    const float* __restrict__ bias, f16* __restrict__ Oh, f16* __restrict__ Ol,
    float* __restrict__ Of, long strideO, double* __restrict__ osum,
    double* __restrict__ osumsq) {
  __shared__ f16 sAh[4096], sAl[4096], sBh[4096], sBl[4096];
  __shared__ float sOut[F32OUT ? 1 : 32 * 132];
  const int tid = threadIdx.x;
  const int w = tid >> 6, l = tid & 63;
  const int bn = blockIdx.x * 128, bm = blockIdx.y * 128;
  const size_t baseA = (size_t)blockIdx.z * strideA;
  const size_t baseB = (size_t)blockIdx.z * strideB;
  const size_t baseO = (size_t)blockIdx.z * strideO;
  const int m0 = (w >> 1) * 64, n0 = (w & 1) * 64;
  char* cAh = (char*)sAh;
  char* cAl = (char*)sAl;
  char* cBh = (char*)sBh;
  char* cBl = (char*)sBl;

  f32x4 acc[4][4], accL[4][4];
#pragma unroll
  for (int i = 0; i < 4; ++i)
#pragma unroll
    for (int j = 0; j < 4; ++j) {
      acc[i][j] = (f32x4){0.f, 0.f, 0.f, 0.f};
      accL[i][j] = (f32x4){0.f, 0.f, 0.f, 0.f};
    }

  for (int kb = 0; kb < K; kb += 32) {
    __syncthreads();  // previous fragment reads done
#pragma unroll
    for (int rep = 0; rep < 2; ++rep) {
      int base = w * 64 + rep * 256;  // wave-uniform linear slot base
      int lin = base + l;
      int s = inv_swz_r2(lin);  // source slot for this lane's linear dest
      int row = s >> 2, ks = s & 3;
      size_t ga = baseA + (size_t)(bm + row) * K + kb + ks * 8;
      size_t gb = baseB + (size_t)(bn + row) * K + kb + ks * 8;
      ld_lds16(Ah + ga, cAh + base * 16);
      ld_lds16(Al + ga, cAl + base * 16);
      ld_lds16(Bh + gb, cBh + base * 16);
      ld_lds16(Bl + gb, cBl + base * 16);
    }
    __syncthreads();  // vmcnt drained; tiles visible
    f16x8 ah[4], al[4];
#pragma unroll
    for (int mf = 0; mf < 4; ++mf) {
      int row = m0 + mf * 16 + (l & 15);
      int byte = swz(row * 64 + ((l >> 4) << 4), row);
      ah[mf] = *(const f16x8*)(cAh + byte);
      al[mf] = *(const f16x8*)(cAl + byte);
    }
#pragma unroll
    for (int nf = 0; nf < 4; ++nf) {
      int row = n0 + nf * 16 + (l & 15);
      int byte = swz(row * 64 + ((l >> 4) << 4), row);
      f16x8 bh = *(const f16x8*)(cBh + byte);
      f16x8 bl = *(const f16x8*)(cBl + byte);
#pragma unroll
      for (int mf = 0; mf < 4; ++mf)
        acc[mf][nf] = MFMA(ah[mf], bh, acc[mf][nf]);
#pragma unroll
      for (int mf = 0; mf < 4; ++mf)
        accL[mf][nf] = MFMA(al[mf], bh, accL[mf][nf]);
#pragma unroll
      for (int mf = 0; mf < 4; ++mf)
        accL[mf][nf] = MFMA(ah[mf], bl, accL[mf][nf]);
    }
  }

  if (F32OUT) {
#pragma unroll
    for (int mf = 0; mf < 4; ++mf)
#pragma unroll
      for (int r = 0; r < 4; ++r) {
        int mrow = bm + m0 + mf * 16 + ((l >> 4) << 2) + r;
        float bv = bias[mrow];
        double s = 0.0, q = 0.0;
#pragma unroll
        for (int nf = 0; nf < 4; ++nf) {
          float v = acc[mf][nf][r] + accL[mf][nf][r] * INV2048 + bv;
          Of[baseO + (size_t)mrow * N + bn + n0 + nf * 16 + (l & 15)] = v;
          s += (double)v;
          q += (double)v * (double)v;
        }
#pragma unroll
        for (int sh = 8; sh >= 1; sh >>= 1) {
          s += __shfl_xor(s, sh);
          q += __shfl_xor(q, sh);
        }
        if ((l & 15) == 0) {
          atomicAdd(&osum[mrow], s);
          atomicAdd(&osumsq[mrow], q);
        }
      }
  } else {
    for (int c = 0; c < 4; ++c) {
      __syncthreads();
      if ((w >> 1) == (c >> 1)) {
#pragma unroll
        for (int mf2 = 0; mf2 < 2; ++mf2) {
          int mf = (c & 1) * 2 + mf2;
          int rl = m0 - c * 32 + mf * 16 + ((l >> 4) << 2);
#pragma unroll
          for (int nf = 0; nf < 4; ++nf)
#pragma unroll
            for (int r = 0; r < 4; ++r)
              sOut[(rl + r) * 132 + n0 + nf * 16 + (l & 15)] =
                  acc[mf][nf][r] + accL[mf][nf][r] * INV2048;
        }
      }
      __syncthreads();
      int row = tid >> 3, cc0 = (tid & 7) * 16;
      size_t gm = bm + c * 32 + row;
      size_t ob = baseO + gm * (size_t)N + bn + cc0;
      f16 hv[16], lv[16];
#pragma unroll
      for (int e = 0; e < 16; ++e) {
        float v = sOut[row * 132 + cc0 + e];
        v += BIAS_N ? bias[bn + cc0 + e] : bias[gm];
        f16 h = (f16)v;
        hv[e] = h;
        lv[e] = (f16)((v - (float)h) * SC2048);
      }
      *(f16x8*)&Oh[ob] = *(f16x8*)hv;
      *(f16x8*)&Oh[ob + 8] = *(f16x8*)(hv + 8);
      *(f16x8*)&Ol[ob] = *(f16x8*)lv;
      *(f16x8*)&Ol[ob + 8] = *(f16x8*)(lv + 8);
    }
  }
}

// ---------------------------------------------------------------------------
// Fused flash attention v5.1 (r13): r12's 8-wave structure (verified) with
// global_load_lds staging (pre-swizzled source, linear LDS dest).
// ---------------------------------------------------------------------------
__global__ __launch_bounds__(512)
    __attribute__((amdgpu_waves_per_eu(2, 2))) void attn_mfma(
        const f16* __restrict__ th_h, const f16* __restrict__ th_l,
        const f16* __restrict__ ph_h, const f16* __restrict__ ph_l,
        const f16* __restrict__ g_h, const f16* __restrict__ g_l,
        f16* __restrict__ y_h, f16* __restrict__ y_l) {
  __shared__ f16 sPhiH[8192], sPhiL[8192];  // phi [32 j][256 c] swizzled
  __shared__ f16 sGH[8192], sGL[8192];      // g   [256 c][32 j] swizzled
  __shared__ float sS[2][64][33];           // combined partial S per K-half
  __shared__ f16 sP[2048], sPl[2048];       // P hi / scaled-lo [64][32]
  __shared__ float sSc[64], sL[64];
  const int tid = threadIdx.x, w = tid >> 6, l = tid & 63;
  const int b = blockIdx.x & 7;
  const int i0 = (blockIdx.x >> 3) * 64;
  const int gq = w >> 2;        // K-half for QK
  const int rw = (w & 3) * 16;  // QK row base

  const size_t tbase =
      ((size_t)b * TT + i0 + rw + (l & 15)) * 256 + gq * 128 + ((l >> 4) << 3);
  f16x8 qh[4], ql[4];
#pragma unroll
  for (int kf = 0; kf < 4; ++kf) {
    qh[kf] = *(const f16x8*)(th_h + tbase + kf * 32);
    ql[kf] = *(const f16x8*)(th_l + tbase + kf * 32);
  }
  f32x4 yacc[4][2], yaccL[4][2];
#pragma unroll
  for (int i = 0; i < 4; ++i)
#pragma unroll
    for (int j = 0; j < 2; ++j) {
      yacc[i][j] = (f32x4){0.f, 0.f, 0.f, 0.f};
      yaccL[i][j] = (f32x4){0.f, 0.f, 0.f, 0.f};
    }
  float mrow[4], lrow[4];
#pragma unroll
  for (int r = 0; r < 4; ++r) {
    mrow[r] = -3e38f;
    lrow[r] = 0.f;
  }

  for (int jc = 0; jc < 64; ++jc) {
    const int j0 = jc * 32;
    // ---- stage phi [32 j][256 c] via global_load_lds (row = slot>>5)
#pragma unroll
    for (int rep = 0; rep < 2; ++rep) {
      int base = w * 64 + rep * 512;
      int lin = base + l;
      int s = inv_swz_r5(lin);
      int row = s >> 5, kq = s & 31;
      size_t ga = ((size_t)b * TT + j0 + row) * 256 + kq * 8;
      ld_lds16(ph_h + ga, (char*)sPhiH + base * 16);
      ld_lds16(ph_l + ga, (char*)sPhiL + base * 16);
    }
    // ---- stage g [256 c][32 j] via global_load_lds (row = slot>>2)
#pragma unroll
    for (int rep = 0; rep < 2; ++rep) {
      int base = w * 64 + rep * 512;
      int lin = base + l;
      int s = inv_swz_r2(lin);
      int row = s >> 2, kq = s & 3;
      size_t ga = ((size_t)b * 256 + row) * TT + j0 + kq * 8;
      ld_lds16(g_h + ga, (char*)sGH + base * 16);
      ld_lds16(g_l + ga, (char*)sGL + base * 16);
    }
    __syncthreads();  // A: vmcnt drained, tiles staged
    // ---- QK^T partial over this wave's 128-channel half
    f32x4 s4[2] = {(f32x4){0.f, 0.f, 0.f, 0.f}, (f32x4){0.f, 0.f, 0.f, 0.f}};
    f32x4 s4L[2] = {(f32x4){0.f, 0.f, 0.f, 0.f}, (f32x4){0.f, 0.f, 0.f, 0.f}};
#pragma unroll
    for (int kf = 0; kf < 4; ++kf) {
#pragma unroll
      for (int jf = 0; jf < 2; ++jf) {
        int prow = jf * 16 + (l & 15);
        int byte =
            swz(prow * 512 + gq * 256 + kf * 64 + ((l >> 4) << 4), prow);
        f16x8 bh = *(const f16x8*)((char*)sPhiH + byte);
        f16x8 bl = *(const f16x8*)((char*)sPhiL + byte);
        s4[jf] = MFMA(qh[kf], bh, s4[jf]);
        s4L[jf] = MFMA(ql[kf], bh, s4L[jf]);
        s4L[jf] = MFMA(qh[kf], bl, s4L[jf]);
      }
    }
#pragma unroll
    for (int jf = 0; jf < 2; ++jf)
#pragma unroll
      for (int r = 0; r < 4; ++r) {
        int row = rw + ((l >> 4) << 2) + r;
        sS[gq][row][jf * 16 + (l & 15)] = s4[jf][r] + s4L[jf][r] * INV2048;
      }
    __syncthreads();  // B: S complete
    // ---- softmax: wave owns rows w*8..w*8+8; lane jcol=l&31
    {
      int jcol = l & 31;
#pragma unroll
      for (int ry = 0; ry < 4; ++ry) {
        int row = w * 8 + (l >> 5) * 4 + ry;
        float sv = sS[0][row][jcol] + sS[1][row][jcol];
        float mx = sv;
#pragma unroll
        for (int sh = 16; sh >= 1; sh >>= 1) mx = fmaxf(mx, __shfl_xor(mx, sh));
        float mn = fmaxf(mrow[ry], mx);
        float sc = __expf(mrow[ry] - mn);
        mrow[ry] = mn;
        float p = __expf(sv - mn);
        float ls = p;
#pragma unroll
        for (int sh = 16; sh >= 1; sh >>= 1) ls += __shfl_xor(ls, sh);
        lrow[ry] = lrow[ry] * sc + ls;
        f16 h = (f16)p;
        *(f16*)((char*)sP + swz(row * 64 + jcol * 2, row)) = h;
        *(f16*)((char*)sPl + swz(row * 64 + jcol * 2, row)) =
            (f16)((p - (float)h) * SC2048);
        if (jcol == 0) sSc[row] = sc;
      }
    }
    __syncthreads();  // C: P + sSc published
    // ---- rescale accumulators
#pragma unroll
    for (int mf = 0; mf < 4; ++mf)
#pragma unroll
      for (int r = 0; r < 4; ++r) {
        float s0 = sSc[mf * 16 + ((l >> 4) << 2) + r];
#pragma unroll
        for (int cf = 0; cf < 2; ++cf) {
          yacc[mf][cf][r] *= s0;
          yaccL[mf][cf][r] *= s0;
        }
      }
    // ---- PV: A=P (all 64 rows), B=g (wave's 32 channels), 3-pass
#pragma unroll
    for (int mf = 0; mf < 4; ++mf) {
      int prow = mf * 16 + (l & 15);
      int pb = swz(prow * 64 + ((l >> 4) << 4), prow);
      f16x8 pa = *(const f16x8*)((char*)sP + pb);
      f16x8 paL = *(const f16x8*)((char*)sPl + pb);
#pragma unroll
      for (int cf = 0; cf < 2; ++cf) {
        int crow = w * 32 + cf * 16 + (l & 15);
        int gb2 = swz(crow * 64 + ((l >> 4) << 4), crow);
        f16x8 gh = *(const f16x8*)((char*)sGH + gb2);
        f16x8 gl = *(const f16x8*)((char*)sGL + gb2);
        yacc[mf][cf] = MFMA(pa, gh, yacc[mf][cf]);
        yaccL[mf][cf] = MFMA(paL, gh, yaccL[mf][cf]);
        yaccL[mf][cf] = MFMA(pa, gl, yaccL[mf][cf]);
      }
    }
    __syncthreads();  // D: P/g reads done before next staging
  }

  // ---- publish final l per row
  if ((l & 31) == 0) {
#pragma unroll
    for (int ry = 0; ry < 4; ++ry) sL[w * 8 + (l >> 5) * 4 + ry] = lrow[ry];
  }
  __syncthreads();
  // ---- epilogue: normalized y via f32 LDS transpose, 4 chunks of 16 rows
  float* sOutF = (float*)sPhiH;
  for (int c2 = 0; c2 < 4; ++c2) {
#pragma unroll
    for (int r = 0; r < 4; ++r) {
      int row = c2 * 16 + ((l >> 4) << 2) + r;
      float linv = 1.f / sL[row];
      int rl = row - c2 * 16;
#pragma unroll
      for (int cf = 0; cf < 2; ++cf)
        sOutF[rl * 264 + w * 32 + cf * 16 + (l & 15)] =
            (yacc[c2][cf][r] + yaccL[c2][cf][r] * INV2048) * linv;
    }
    __syncthreads();
    int row = tid >> 5, cc0 = (tid & 31) * 8;
    size_t ob = ((size_t)b * TT + i0 + c2 * 16 + row) * 256 + cc0;
    f16 hv[8], lv[8];
#pragma unroll
    for (int e = 0; e < 8; ++e) {
      float v = sOutF[row * 264 + cc0 + e];
      f16 h = (f16)v;
      hv[e] = h;
      lv[e] = (f16)((v - (float)h) * SC2048);
    }
    *(f16x8*)&y_h[ob] = *(f16x8*)hv;
    *(f16x8*)&y_l[ob] = *(f16x8*)lv;
    __syncthreads();
  }
}

// ---------------------------------------------------------------------------
__global__ void zero_stats(double* s) { s[threadIdx.x] = 0.0; }

__global__ void bn_stats(const double* __restrict__ osum,
                         const double* __restrict__ osumsq,
                         float* __restrict__ mean, float* __restrict__ rstd) {
  int o = threadIdx.x;
  if (o < CC) {
    const double inv = 1.0 / (double)(BB * TT);
    double mu = osum[o] * inv;
    double var = osumsq[o] * inv - mu * mu;
    mean[o] = (float)mu;
    rstd[o] = (float)(1.0 / sqrt(var + (double)EPSV));
  }
}

__global__ __launch_bounds__(256) void bn_apply(
    float* __restrict__ out, const float* __restrict__ x,
    const float* __restrict__ mean, const float* __restrict__ rstd,
    const float* __restrict__ gamma, const float* __restrict__ beta) {
  const size_t n4 = (size_t)BB * CC * TT / 4;
  for (size_t idx = (size_t)blockIdx.x * blockDim.x + threadIdx.x; idx < n4;
       idx += (size_t)gridDim.x * blockDim.x) {
    size_t e = idx * 4;
    int o = (int)((e / TT) % CC);
    float4 wv = ((const float4*)out)[idx];
    float4 xv = ((const float4*)x)[idx];
    float mu = mean[o], rs = rstd[o], ga = gamma[o], be = beta[o];
    float4 r;
    r.x = fmaxf((wv.x - mu) * rs * ga + be, 0.f) + xv.x;
    r.y = fmaxf((wv.y - mu) * rs * ga + be, 0.f) + xv.y;
    r.z = fmaxf((wv.z - mu) * rs * ga + be, 0.f) + xv.z;
    r.w = fmaxf((wv.w - mu) * rs * ga + be, 0.f) + xv.w;
    ((float4*)out)[idx] = r;
  }
}

// ===========================================================================
// Fallback fp32 path (round-3, known-good) — used if ws too small.
// ===========================================================================
template <int M, int K, bool STATS>
__global__ __launch_bounds__(256) void gemm_proj(
    const float* __restrict__ W, const float* __restrict__ bias,
    const float* __restrict__ X, float* __restrict__ Out,
    double* __restrict__ osum, double* __restrict__ osumsq) {
  __shared__ float Ws[16][65];
  __shared__ float Xs[16][65];
  const int bt = blockIdx.x * 64, bm = blockIdx.y * 64, b = blockIdx.z;
  const int tid = threadIdx.x, tx = tid & 15, ty = tid >> 4;
  const float* Xb = X + (size_t)b * K * TT;
  float acc[4][4] = {};
  for (int kb = 0; kb < K; kb += 16) {
#pragma unroll
    for (int r = 0; r < 4; ++r) {
      int idx = tid + r * 256;
      int m = idx >> 4, k = idx & 15;
      Ws[k][m] = W[(size_t)(bm + m) * K + kb + k];
      int kx = idx >> 6, t = idx & 63;
      Xs[kx][t] = Xb[(size_t)(kb + kx) * TT + bt + t];
    }
    __syncthreads();
#pragma unroll
    for (int k = 0; k < 16; ++k) {
      float a[4], bv[4];
#pragma unroll
      for (int i = 0; i < 4; ++i) a[i] = Ws[k][ty * 4 + i];
#pragma unroll
      for (int j = 0; j < 4; ++j) bv[j] = Xs[k][tx * 4 + j];
#pragma unroll
      for (int i = 0; i < 4; ++i)
#pragma unroll
        for (int j = 0; j < 4; ++j) acc[i][j] += a[i] * bv[j];
    }
    __syncthreads();
  }
#pragma unroll
  for (int i = 0; i < 4; ++i) {
    int m = bm + ty * 4 + i;
    float bv = bias[m];
    double rs = 0.0, rq = 0.0;
#pragma unroll
    for (int j = 0; j < 4; ++j) {
      float v = acc[i][j] + bv;
      Out[((size_t)b * M + m) * TT + bt + tx * 4 + j] = v;
      if (STATS) {
        rs += (double)v;
        rq += (double)v * (double)v;
      }
    }
    if (STATS) {
#pragma unroll
      for (int s = 8; s >= 1; s >>= 1) {
        rs += __shfl_xor(rs, s, 16);
        rq += __shfl_xor(rq, s, 16);
      }
      if (tx == 0) {
        atomicAdd(&osum[m], rs);
        atomicAdd(&osumsq[m], rq);
      }
    }
  }
}

__global__ __launch_bounds__(256) void attn_flash(
    const float* __restrict__ th, const float* __restrict__ ph,
    const float* __restrict__ gx, float* __restrict__ y) {
  __shared__ float As[16][65];
  __shared__ float Bs[16][65];
  __shared__ float Ps[64][65];
  __shared__ float Gs[64][65];
  __shared__ float mScale[64];
  __shared__ float lArr[64];
  const int i0 = blockIdx.x * 64, b = blockIdx.y;
  const int tid = threadIdx.x, tx = tid & 15, ty = tid >> 4;
  const float* thb = th + (size_t)b * ICC * TT;
  const float* phb = ph + (size_t)b * ICC * TT;
  const float* gb = gx + (size_t)b * ICC * TT;
  float m[4], l[4];
#pragma unroll
  for (int i = 0; i < 4; ++i) {
    m[i] = -1e30f;
    l[i] = 0.f;
  }
  float acc[4][4][4] = {};
  for (int j0 = 0; j0 < TT; j0 += 64) {
    float S[4][4] = {};
    for (int cb = 0; cb < ICC; cb += 16) {
#pragma unroll
      for (int r = 0; r < 4; ++r) {
        int idx = tid + r * 256;
        int k = idx >> 6, col = idx & 63;
        As[k][col] = thb[(size_t)(cb + k) * TT + i0 + col];
        Bs[k][col] = phb[(size_t)(cb + k) * TT + j0 + col];
      }
      __syncthreads();
#pragma unroll
      for (int k = 0; k < 16; ++k) {
        float a[4], bv[4];
#pragma unroll
        for (int i = 0; i < 4; ++i) a[i] = As[k][ty * 4 + i];
#pragma unroll
        for (int j = 0; j < 4; ++j) bv[j] = Bs[k][tx * 4 + j];
#pragma unroll
        for (int i = 0; i < 4; ++i)
#pragma unroll
          for (int j = 0; j < 4; ++j) S[i][j] += a[i] * bv[j];
      }
      __syncthreads();
    }
    float sc[4];
#pragma unroll
    for (int i = 0; i < 4; ++i) {
      float mc = S[i][0];
#pragma unroll
      for (int j = 1; j < 4; ++j) mc = fmaxf(mc, S[i][j]);
#pragma unroll
      for (int s = 8; s >= 1; s >>= 1) mc = fmaxf(mc, __shfl_xor(mc, s, 16));
      float mn = fmaxf(m[i], mc);
      sc[i] = __expf(m[i] - mn);
      float lsum = 0.f;
#pragma unroll
      for (int j = 0; j < 4; ++j) {
        float p = __expf(S[i][j] - mn);
        S[i][j] = p;
        lsum += p;
      }
#pragma unroll
      for (int s = 8; s >= 1; s >>= 1) lsum += __shfl_xor(lsum, s, 16);
      l[i] = l[i] * sc[i] + lsum;
      m[i] = mn;
#pragma unroll
      for (int j = 0; j < 4; ++j) Ps[ty * 4 + i][tx * 4 + j] = S[i][j];
    }
    if (tx == 0) {
#pragma unroll
      for (int i = 0; i < 4; ++i) mScale[ty * 4 + i] = sc[i];
    }
    __syncthreads();
#pragma unroll
    for (int cq = 0; cq < 4; ++cq) {
#pragma unroll
      for (int r = 0; r < 16; ++r) {
        int idx = tid + r * 256;
        int cpr = idx >> 6, j = idx & 63;
        Gs[cpr][j] = gb[(size_t)(cq * 64 + cpr) * TT + j0 + j];
      }
      __syncthreads();
      float scj[4];
#pragma unroll
      for (int jq = 0; jq < 4; ++jq) scj[jq] = mScale[tx * 4 + jq];
#pragma unroll
      for (int ci = 0; ci < 4; ++ci)
#pragma unroll
        for (int jq = 0; jq < 4; ++jq) acc[cq][ci][jq] *= scj[jq];
      for (int j = 0; j < 64; ++j) {
        float a[4], p[4];
#pragma unroll
        for (int ci = 0; ci < 4; ++ci) a[ci] = Gs[ty * 4 + ci][j];
#pragma unroll
        for (int jq = 0; jq < 4; ++jq) p[jq] = Ps[tx * 4 + jq][j];
#pragma unroll
        for (int ci = 0; ci < 4; ++ci)
#pragma unroll
          for (int jq = 0; jq < 4; ++jq) acc[cq][ci][jq] += a[ci] * p[jq];
      }
      __syncthreads();
    }
  }
  if (tx == 0) {
#pragma unroll
    for (int i = 0; i < 4; ++i) lArr[ty * 4 + i] = l[i];
  }
  __syncthreads();
  float linv[4];
#pragma unroll
  for (int jq = 0; jq < 4; ++jq) linv[jq] = 1.f / lArr[tx * 4 + jq];
#pragma unroll
  for (int cq = 0; cq < 4; ++cq)
#pragma unroll
    for (int ci = 0; ci < 4; ++ci)
#pragma unroll
      for (int jq = 0; jq < 4; ++jq)
        y[((size_t)b * ICC + cq * 64 + ty * 4 + ci) * TT + i0 + tx * 4 + jq] =
            acc[cq][ci][jq] * linv[jq];
}

// ---------------------------------------------------------------------------
extern "C" void kernel_launch(void* const* d_in, const int* in_sizes, int n_in,
                              void* d_out, int out_size, void* d_ws,
                              size_t ws_size, hipStream_t stream) {
  const float* x = (const float*)d_in[0];
  const float* g_w = (const float*)d_in[1];
  const float* g_b = (const float*)d_in[2];
  const float* th_w = (const float*)d_in[3];
  const float* th_b = (const float*)d_in[4];
  const float* ph_w = (const float*)d_in[5];
  const float* ph_b = (const float*)d_in[6];
  const float* W_w = (const float*)d_in[7];
  const float* W_b = (const float*)d_in[8];
  const float* gamma = (const float*)d_in[9];
  const float* beta = (const float*)d_in[10];
  float* out = (float*)d_out;
  dim3 blk(256);

  const size_t NP = (size_t)BB * TT * ICC;  // 4,194,304
  const size_t NW = 131072;                 // 256*512
  const size_t need = (8 * NP + 8 * NW) * sizeof(f16) + 8192 + 4096;

  if (ws_size >= need) {
    // ---------------- fast MFMA path ----------------
    f16* p = (f16*)d_ws;
    f16 *thH = p, *thL = thH + NP, *phH = thL + NP, *phL = phH + NP;
    f16 *gH = phL + NP, *gL = gH + NP, *yH = gL + NP, *yL = yH + NP;
    f16* wp = yL + NP;
    f16 *gwH = wp, *gwL = gwH + NW, *twH = gwL + NW, *twL = twH + NW;
    f16 *pwH = twL + NW, *pwL = pwH + NW, *wwH = pwL + NW, *wwL = wwH + NW;
    double* statd = (double*)(wwL + NW);
    float* meanb = (float*)(statd + 1024);
    float* rstdb = meanb + 512;
    f16* xTh = (f16*)d_out;  // xT hi/lo lives in d_out (dead before W-conv)
    f16* xTl = xTh + (size_t)BB * TT * CC;

    split_transpose_x<<<dim3(TT / 32, CC / 32, BB), dim3(32, 8), 0, stream>>>(
        x, xTh, xTl);
    split_w<<<512, 256, 0, stream>>>(g_w, gwH, gwL, (int)NW);
    split_w<<<512, 256, 0, stream>>>(th_w, twH, twL, (int)NW);
    split_w<<<512, 256, 0, stream>>>(ph_w, pwH, pwL, (int)NW);
    split_w<<<512, 256, 0, stream>>>(W_w, wwH, wwL, (int)NW);
    zero_stats<<<1, 1024, 0, stream>>>(statd);

    // theta/phi: D[t][ic] = xT * W^T   (M=T, N=IC, K=C, bias on N)
    gemm_nt<TT, ICC, CC, true, false><<<dim3(2, 16, BB), blk, 0, stream>>>(
        xTh, xTl, (long)TT * CC, twH, twL, 0, th_b, thH, thL, nullptr,
        (long)TT * ICC, nullptr, nullptr);
    gemm_nt<TT, ICC, CC, true, false><<<dim3(2, 16, BB), blk, 0, stream>>>(
        xTh, xTl, (long)TT * CC, pwH, pwL, 0, ph_b, phH, phL, nullptr,
        (long)TT * ICC, nullptr, nullptr);
    // g: D[ic][t] = Wg * xT^T   (M=IC, N=T, K=C, bias on M)
    gemm_nt<ICC, TT, CC, false, false><<<dim3(16, 2, BB), blk, 0, stream>>>(
        gwH, gwL, 0, xTh, xTl, (long)TT * CC, g_b, gH, gL, nullptr,
        (long)ICC * TT, nullptr, nullptr);
    // attention -> y f16 hi/lo directly (8-wave blocks)
    attn_mfma<<<256, dim3(512), 0, stream>>>(thH, thL, phH, phL, gH, gL, yH,
                                             yL);
    // W conv: D[o][t] -> d_out + BN stats  (M=C, N=T, K=IC, bias on M)
    gemm_nt<CC, TT, ICC, false, true><<<dim3(16, 4, BB), blk, 0, stream>>>(
        wwH, wwL, 0, yH, yL, (long)TT * ICC, W_b, nullptr, nullptr, out,
        (long)CC * TT, statd, statd + CC);
    bn_stats<<<1, 512, 0, stream>>>(statd, statd + CC, meanb, rstdb);
    bn_apply<<<2048, 256, 0, stream>>>(out, x, meanb, rstdb, gamma, beta);
  } else {
    // ---------------- fallback fp32 path ----------------
    float* ws = (float*)d_ws;
    const size_t np = (size_t)BB * ICC * TT;
    float* thb = ws;
    float* phb = ws + np;
    float* gbuf = ws + 2 * np;
    float* yb = thb;
    double* statd = (double*)(ws + 3 * np);
    float* meanb = (float*)(statd + 1024);
    float* rstdb = meanb + 512;
    gemm_proj<ICC, CC, false><<<dim3(TT / 64, ICC / 64, BB), blk, 0, stream>>>(
        th_w, th_b, x, thb, nullptr, nullptr);
    gemm_proj<ICC, CC, false><<<dim3(TT / 64, ICC / 64, BB), blk, 0, stream>>>(
        ph_w, ph_b, x, phb, nullptr, nullptr);
    gemm_proj<ICC, CC, false><<<dim3(TT / 64, ICC / 64, BB), blk, 0, stream>>>(
        g_w, g_b, x, gbuf, nullptr, nullptr);
    attn_flash<<<dim3(TT / 64, BB), blk, 0, stream>>>(thb, phb, gbuf, yb);
    zero_stats<<<1, 1024, 0, stream>>>(statd);
    gemm_proj<CC, ICC, true><<<dim3(TT / 64, CC / 64, BB), blk, 0, stream>>>(
        W_w, W_b, yb, out, statd, statd + CC);
    bn_stats<<<1, 512, 0, stream>>>(statd, statd + CC, meanb, rstdb);
    bn_apply<<<2048, 256, 0, stream>>>(out, x, meanb, rstdb, gamma, beta);
  }
}